// Round 9
// baseline (638.828 us; speedup 1.0000x reference)
//
#include <hip/hip_runtime.h>
#include <cstdint>
#include <cstddef>

#define TDIM 4096       // B*S tokens
#define DDIM 1024
#define HDIM 4096
#define EDIM 8
#define CAPD 2048
#define NSLOT 8192      // T*K
#define NROUTERBLK 1024

typedef _Float16 f16;
typedef _Float16 f16x2 __attribute__((ext_vector_type(2)));
typedef _Float16 f16x4 __attribute__((ext_vector_type(4)));
typedef _Float16 f16x8 __attribute__((ext_vector_type(8)));
typedef float f32x4 __attribute__((ext_vector_type(4)));

__device__ __forceinline__ void gload16(const void* g, void* l) {
  __builtin_amdgcn_global_load_lds(
      (const __attribute__((address_space(1))) unsigned int*)g,
      (__attribute__((address_space(3))) unsigned int*)l, 16, 0, 0);
}

__device__ __forceinline__ float gelu_fast(float x) {
  float y = 1.5957691216057308f * (x + 0.044715f * x * x * x);
  y = fminf(y, 60.f);
  float e = __expf(y);
  return x * e * __builtin_amdgcn_rcpf(e + 1.f);
}

#define MEMFENCE asm volatile("" ::: "memory")
#define VMCNT(n) asm volatile("s_waitcnt vmcnt(" #n ")" ::: "memory")
#define BAR_ENTER MEMFENCE; __builtin_amdgcn_s_barrier(); \
  asm volatile("s_waitcnt lgkmcnt(0)" ::: "memory")
#define BAR_EXIT __builtin_amdgcn_s_barrier(); MEMFENCE

// ---------------- transpose + f32->f16 convert: src (E,R,C) -> dst (E,C,R) ----------------
__global__ __launch_bounds__(256)
void transpose_cvt(const float* __restrict__ src, f16* __restrict__ dst, int R, int C) {
  __shared__ float tile[64][65];
  const int e = blockIdx.z;
  const int c0 = blockIdx.x * 64, r0 = blockIdx.y * 64;
  const int tid = threadIdx.x;
  const float* s = src + (size_t)e * R * C;
  f16* d = dst + (size_t)e * R * C;
  #pragma unroll
  for (int p = 0; p < 4; ++p) {
    const int row = p * 16 + (tid >> 4);
    const int col = (tid & 15) * 4;
    float4 v = *(const float4*)(s + (size_t)(r0 + row) * C + c0 + col);
    tile[row][col] = v.x; tile[row][col + 1] = v.y;
    tile[row][col + 2] = v.z; tile[row][col + 3] = v.w;
  }
  __syncthreads();
  #pragma unroll
  for (int p = 0; p < 4; ++p) {
    const int crow = p * 16 + (tid >> 4);
    const int q = (tid & 15) * 4;
    f16x4 o;
    #pragma unroll
    for (int j = 0; j < 4; ++j) o[j] = (f16)tile[q + j][crow];
    *(f16x4*)(d + (size_t)(c0 + crow) * R + r0 + q) = o;
  }
}

// ---------------- router ----------------
__global__ void router_k(const float* __restrict__ x, const float* __restrict__ rw,
                         int* __restrict__ eidx, float* __restrict__ gates,
                         float* __restrict__ bps) {
  __shared__ float lrw[EDIM * DDIM];
  __shared__ float wps[4][EDIM];
  const int tid = threadIdx.x, lane = tid & 63, wv = tid >> 6;
  for (int i = tid; i < EDIM * DDIM; i += 256) lrw[i] = rw[i];
  __syncthreads();
  const int t = blockIdx.x * 4 + wv;
  float acc[EDIM];
  #pragma unroll
  for (int e = 0; e < EDIM; ++e) acc[e] = 0.f;
  const float* xr = x + (size_t)t * DDIM;
  #pragma unroll
  for (int j = 0; j < DDIM / 64; ++j) {
    float xv = xr[j * 64 + lane];
    #pragma unroll
    for (int e = 0; e < EDIM; ++e) acc[e] += xv * lrw[e * DDIM + j * 64 + lane];
  }
  #pragma unroll
  for (int off = 32; off >= 1; off >>= 1) {
    #pragma unroll
    for (int e = 0; e < EDIM; ++e) acc[e] += __shfl_xor(acc[e], off);
  }
  float mx = acc[0];
  #pragma unroll
  for (int e = 1; e < EDIM; ++e) mx = fmaxf(mx, acc[e]);
  float p[EDIM], s = 0.f;
  #pragma unroll
  for (int e = 0; e < EDIM; ++e) { p[e] = expf(acc[e] - mx); s += p[e]; }
  float inv = 1.f / s;
  #pragma unroll
  for (int e = 0; e < EDIM; ++e) p[e] *= inv;
  int i1 = 0; float p1 = p[0];
  #pragma unroll
  for (int e = 1; e < EDIM; ++e) if (p[e] > p1) { p1 = p[e]; i1 = e; }
  int i2 = (i1 == 0) ? 1 : 0; float p2 = p[i2];
  #pragma unroll
  for (int e = 0; e < EDIM; ++e) if (e != i1 && p[e] > p2) { p2 = p[e]; i2 = e; }
  float gs = 1.f / (p1 + p2);
  if (lane == 0) {
    eidx[2 * t] = i1; eidx[2 * t + 1] = i2;
    gates[2 * t] = p1 * gs; gates[2 * t + 1] = p2 * gs;
    #pragma unroll
    for (int e = 0; e < EDIM; ++e) wps[wv][e] = p[e];
  }
  __syncthreads();
  if (tid < EDIM)
    bps[blockIdx.x * EDIM + tid] = wps[0][tid] + wps[1][tid] + wps[2][tid] + wps[3][tid];
}

// ---------------- per-chunk expert histogram ----------------
__global__ void count_k(const int* __restrict__ eidx, int* __restrict__ cc) {
  __shared__ int h[EDIM];
  const int tid = threadIdx.x;
  if (tid < EDIM) h[tid] = 0;
  __syncthreads();
  atomicAdd(&h[eidx[blockIdx.x * 256 + tid]], 1);
  __syncthreads();
  if (tid < EDIM) cc[blockIdx.x * EDIM + tid] = h[tid];
}

// ---------------- scan chunks, totals, lb_loss ----------------
__global__ void scan_k(const int* __restrict__ cc, const float* __restrict__ bps,
                       int* __restrict__ cb, int* __restrict__ counts,
                       int* __restrict__ rowsNeeded, float* __restrict__ lb_out) {
  __shared__ float red[32][EDIM];
  __shared__ int cnt_s[EDIM];
  const int tid = threadIdx.x;
  const int e = tid & 7, g = tid >> 3;
  float s = 0.f;
  for (int j = 0; j < 32; ++j) s += bps[(g + 32 * j) * EDIM + e];
  red[g][e] = s;
  __syncthreads();
  for (int st = 16; st >= 1; st >>= 1) {
    if (g < st) red[g][e] += red[g + st][e];
    __syncthreads();
  }
  if (tid < EDIM) {
    int base = 0;
    for (int c = 0; c < 32; ++c) { cb[c * EDIM + tid] = base; base += cc[c * EDIM + tid]; }
    counts[tid] = base;
    rowsNeeded[tid] = base < CAPD ? base : CAPD;
    cnt_s[tid] = base;
  }
  __syncthreads();
  if (tid == 0) {
    float lb = 0.f;
    for (int ee = 0; ee < EDIM; ++ee)
      lb += (red[0][ee] / (float)TDIM) * ((float)cnt_s[ee] / (float)NSLOT);
    lb_out[0] = lb * (float)EDIM;
  }
}

// ---------------- per-slot position via wave ballots (deterministic) ----------------
__global__ void pos_k(const int* __restrict__ eidx, const float* __restrict__ gates,
                      const int* __restrict__ cb, int* __restrict__ posa,
                      float* __restrict__ wslot) {
  __shared__ int wcnt[4][EDIM];
  const int tid = threadIdx.x, lane = tid & 63, wv = tid >> 6;
  const int slot = blockIdx.x * 256 + tid;
  const int e = eidx[slot];
  const unsigned long long below = (1ull << lane) - 1ull;
  int wavepos = 0;
  #pragma unroll
  for (int ee = 0; ee < EDIM; ++ee) {
    unsigned long long m = __ballot(e == ee);
    if (lane == 0) wcnt[wv][ee] = __popcll(m);
    if (e == ee) wavepos = __popcll(m & below);
  }
  __syncthreads();
  int off = 0;
  for (int w = 0; w < wv; ++w) off += wcnt[w][e];
  const int pos = cb[blockIdx.x * EDIM + e] + off + wavepos;
  posa[slot] = pos;
  wslot[slot] = (pos < CAPD) ? gates[slot] : 0.f;
}

// ---------------- scatter token rows -> f16 expert buffers ----------------
__global__ void scatter_k(const float* __restrict__ x, const int* __restrict__ eidx,
                          const int* __restrict__ posa, f16* __restrict__ buf) {
  const int s = blockIdx.x, lane = threadIdx.x;
  const int p = posa[s];
  if (p >= CAPD) return;
  const int e = eidx[s], tok = s >> 1;
  const float4* src = (const float4*)(x + (size_t)tok * DDIM);
  f16x4* dst = (f16x4*)(buf + ((size_t)e * CAPD + p) * DDIM);
  #pragma unroll
  for (int j = 0; j < DDIM / 4 / 64; ++j) {
    float4 v = src[j * 64 + lane];
    f16x4 o; o.x = (f16)v.x; o.y = (f16)v.y; o.z = (f16)v.z; o.w = (f16)v.w;
    dst[j * 64 + lane] = o;
  }
}

// ============ 256x256 f16 MFMA GEMM — r7 8-phase schedule + hoisted LDS offsets ============
// VAR=0: real kernel. VAR=1: no in-loop staging/vmcnt (diagnostic, wrong data, scratch out).
// VAR=2: additionally no in-loop ds_reads (barrier+MFMA floor). Rule #17: MFMA chain keeps
// everything live (acc -> epilogue store); staging is a side-effecting builtin (no DCE).
#define LDA_(bb, MH, AF) do { \
    _Pragma("unroll") for (int m_ = 0; m_ < 4; ++m_) \
    _Pragma("unroll") for (int k_ = 0; k_ < 2; ++k_) \
      (AF)[m_][k_] = *(const f16x8*)(smem + aoffs[bb][m_][k_] + (MH) * 8192); \
  } while (0)

#define LDB_(bb, NH, BF) do { \
    _Pragma("unroll") for (int n_ = 0; n_ < 2; ++n_) \
    _Pragma("unroll") for (int k_ = 0; k_ < 2; ++k_) \
      (BF)[n_][k_] = *(const f16x8*)(smem + boffs[bb][n_][k_] + (NH) * 4096); \
  } while (0)

#define MM16_(AM, AN, BF) do { \
    __builtin_amdgcn_s_setprio(1); \
    _Pragma("unroll") for (int m_ = 0; m_ < 4; ++m_) \
    _Pragma("unroll") for (int n_ = 0; n_ < 2; ++n_) \
    _Pragma("unroll") for (int k_ = 0; k_ < 2; ++k_) \
      acc[(AM) + m_][(AN) + n_] = __builtin_amdgcn_mfma_f32_16x16x32_f16( \
          af[m_][k_], (BF)[n_][k_], acc[(AM) + m_][(AN) + n_], 0, 0, 0); \
    __builtin_amdgcn_s_setprio(0); \
  } while (0)

// hh2: 0=A-half0, 1=A-half1, 2=B-half0, 3=B-half1; g = K-tile index
#define STAGE(bb, hh2, g) do { \
    const f16* s_ = sP[hh2] + (g) * 64; \
    char* d_ = smem + (bb) * 65536 + (hh2) * 16384 + wv * 1024; \
    gload16(s_, d_); \
    gload16(s_ + (size_t)64 * LD, d_ + 8192); \
  } while (0)

template<int KLEN, int LD, int N, int GELU, int NT, int NKS, int VAR = 0>
__global__ __launch_bounds__(512, 1)
void gemm256p(const f16* __restrict__ A, const f16* __restrict__ Bt,
              const float* __restrict__ bias, f16* __restrict__ C, size_t pstride,
              const int* __restrict__ rowsNeeded) {
  constexpr int NI = KLEN / 128;           // iterations, 2 K-tiles each (NI >= 2)
  __shared__ __align__(128) char smem[131072];
  const int wg = blockIdx.x;
  const int e = wg & 7;
  const int r = wg >> 3;
  const int nt = r % NT;
  const int ks = (r / NT) % NKS;
  const int mt = r / (NT * NKS);
  if (mt * 256 >= rowsNeeded[e]) return;
  const int tid = threadIdx.x, lane = tid & 63, wv = tid >> 6;
  const int wr = wv >> 2, wc = wv & 3;     // 2 x 4 wave grid
  const int ro = lane & 15, q4 = (lane >> 4) * 4;
  const int ko0b = (lane >> 4) * 16;       // k-offset bytes within row
  const f16* aBase = A + ((size_t)e * CAPD + (size_t)mt * 256) * LD + (size_t)ks * KLEN;
  const f16* bBase = Bt + ((size_t)e * N + (size_t)nt * 256) * LD + (size_t)ks * KLEN;
  const int row0 = tid >> 3;               // 0..63 (second gload does row0+64)
  const int sw0 = ((tid & 7) ^ (row0 & 7)) * 8;   // pre-swizzled source col (elements)

  // hoisted global staging bases (per hh2)
  const f16* sP[4];
  sP[0] = aBase + (size_t)row0 * LD + sw0;
  sP[1] = sP[0] + (size_t)128 * LD;
  sP[2] = bBase + (size_t)row0 * LD + sw0;
  sP[3] = sP[2] + (size_t)128 * LD;

  // hoisted LDS read byte-offsets (loop-invariant; statically indexed -> registers)
  int aoffs[2][4][2], boffs[2][2][2];
  #pragma unroll
  for (int bb = 0; bb < 2; ++bb) {
    #pragma unroll
    for (int m = 0; m < 4; ++m)
      #pragma unroll
      for (int k = 0; k < 2; ++k) {
        const int rh = m * 16 + ro;
        aoffs[bb][m][k] = bb * 65536 + wr * 16384 + rh * 128 +
                          ((k * 64 + ko0b) ^ ((rh & 7) << 4));
      }
    #pragma unroll
    for (int n = 0; n < 2; ++n)
      #pragma unroll
      for (int k = 0; k < 2; ++k) {
        const int rh = (wc & 1) * 64 + n * 16 + ro;
        boffs[bb][n][k] = bb * 65536 + (2 + (wc >> 1)) * 16384 + rh * 128 +
                          ((k * 64 + ko0b) ^ ((rh & 7) << 4));
      }
  }

  f16x8 af[4][2], bf0[2][2], bf1[2][2];
  f32x4 acc[8][4];
  #pragma unroll
  for (int m = 0; m < 8; ++m)
    #pragma unroll
    for (int n = 0; n < 4; ++n) acc[m][n] = (f32x4){0.f, 0.f, 0.f, 0.f};

  // ---- prologue
  if constexpr (VAR == 0) {
    STAGE(0, 2, 0); STAGE(0, 3, 0); STAGE(0, 0, 0); STAGE(0, 1, 0);
    STAGE(1, 2, 1); STAGE(1, 3, 1);
    VMCNT(4);                               // tile0's 8 loads landed
    __builtin_amdgcn_s_barrier(); MEMFENCE;
  } else {
    STAGE(0, 0, 0); STAGE(0, 1, 0); STAGE(0, 2, 0); STAGE(0, 3, 0);
    STAGE(1, 0, 1); STAGE(1, 1, 1); STAGE(1, 2, 1); STAGE(1, 3, 1);
    VMCNT(0);
    __builtin_amdgcn_s_barrier(); MEMFENCE;
    if constexpr (VAR == 2) {               // one-time frag loads (kept live by MFMAs)
      LDA_(0, 0, af); LDB_(0, 0, bf0); LDB_(0, 1, bf1);
      asm volatile("s_waitcnt lgkmcnt(0)" ::: "memory");
    }
  }

  #pragma unroll 1
  for (int i = 0; i < NI - 1; ++i) {
    const int g0 = 2 * i;
    // P0
    if constexpr (VAR < 2) { LDA_(0, 0, af); LDB_(0, 0, bf0); }
    if constexpr (VAR == 0) STAGE(1, 0, g0 + 1);
    BAR_ENTER; MM16_(0, 0, bf0); BAR_EXIT;
    // P1
    if constexpr (VAR < 2) LDB_(0, 1, bf1);
    if constexpr (VAR == 0) STAGE(1, 1, g0 + 1);
    BAR_ENTER; MM16_(0, 2, bf1); BAR_EXIT;
    // P2
    if constexpr (VAR < 2) LDA_(0, 1, af);
    if constexpr (VAR == 0) STAGE(0, 2, g0 + 2);
    BAR_ENTER; MM16_(4, 2, bf1); BAR_EXIT;
    // P3
    if constexpr (VAR == 0) { STAGE(0, 3, g0 + 2); VMCNT(4); }
    BAR_ENTER; MM16_(4, 0, bf0); BAR_EXIT;
    // P4 (tile g1, buf1)
    if constexpr (VAR < 2) { LDA_(1, 0, af); LDB_(1, 0, bf0); }
    if constexpr (VAR == 0) STAGE(0, 0, g0 + 2);
    BAR_ENTER; MM16_(0, 0, bf0); BAR_EXIT;
    // P5
    if constexpr (VAR < 2) LDB_(1, 1, bf1);
    if constexpr (VAR == 0) STAGE(0, 1, g0 + 2);
    BAR_ENTER; MM16_(0, 2, bf1); BAR_EXIT;
    // P6
    if constexpr (VAR < 2) LDA_(1, 1, af);
    if constexpr (VAR == 0) STAGE(1, 2, g0 + 3);
    BAR_ENTER; MM16_(4, 2, bf1); BAR_EXIT;
    // P7
    if constexpr (VAR == 0) { STAGE(1, 3, g0 + 3); VMCNT(4); }
    BAR_ENTER; MM16_(4, 0, bf0); BAR_EXIT;
  }
  // ---- last iter
  {
    const int g1 = 2 * NI - 1;
    if constexpr (VAR < 2) { LDA_(0, 0, af); LDB_(0, 0, bf0); }
    if constexpr (VAR == 0) STAGE(1, 0, g1);
    BAR_ENTER; MM16_(0, 0, bf0); BAR_EXIT;
    if constexpr (VAR < 2) LDB_(0, 1, bf1);
    if constexpr (VAR == 0) STAGE(1, 1, g1);
    BAR_ENTER; MM16_(0, 2, bf1); BAR_EXIT;
    if constexpr (VAR < 2) LDA_(0, 1, af);
    BAR_ENTER; MM16_(4, 2, bf1); BAR_EXIT;
    if constexpr (VAR == 0) VMCNT(0);
    BAR_ENTER; MM16_(4, 0, bf0); BAR_EXIT;
    if constexpr (VAR < 2) { LDA_(1, 0, af); LDB_(1, 0, bf0); }
    BAR_ENTER; MM16_(0, 0, bf0); BAR_EXIT;
    if constexpr (VAR < 2) LDB_(1, 1, bf1);
    BAR_ENTER; MM16_(0, 2, bf1); BAR_EXIT;
    if constexpr (VAR < 2) LDA_(1, 1, af);
    BAR_ENTER; MM16_(4, 2, bf1); BAR_EXIT;
    BAR_ENTER; MM16_(4, 0, bf0); BAR_EXIT;   // barrier before epilogue LDS reuse
  }

  // ---- epilogue: per-wave 16KB LDS region, swizzled conflict-free, coalesced stores
  float bv[4];
  #pragma unroll
  for (int n = 0; n < 4; ++n)
    bv[n] = (ks == 0) ? bias[e * N + nt * 256 + wc * 64 + n * 16 + ro] : 0.f;
  f16* Ct = (f16*)(smem + wv * 16384);      // [128][64] f16, col-byte ^= ((row>>2)&3)<<5
  #pragma unroll
  for (int m = 0; m < 8; ++m)
    #pragma unroll
    for (int n = 0; n < 4; ++n)
      #pragma unroll
      for (int i = 0; i < 4; ++i) {
        const int row = m * 16 + q4 + i;
        float v = acc[m][n][i] + bv[n];
        if (GELU) v = gelu_fast(v);
        *(f16*)((char*)Ct + row * 128 + ((((n * 16 + ro) * 2)) ^ (((row >> 2) & 3) << 5))) = (f16)v;
      }
  asm volatile("s_waitcnt lgkmcnt(0)" ::: "memory");
  f16* Cp = C + (size_t)ks * pstride;
  const size_t crow0 = (size_t)e * CAPD + mt * 256 + wr * 128;
  const int ccol0 = nt * 256 + wc * 64;
  #pragma unroll
  for (int j = 0; j < 16; ++j) {
    const int idx = j * 64 + lane;
    const int rr = idx >> 3, c2 = (idx & 7) * 16;
    f16x8 v = *(const f16x8*)((const char*)Ct + rr * 128 + (c2 ^ (((rr >> 2) & 3) << 5)));
    *(f16x8*)(Cp + (crow0 + rr) * N + ccol0 + (idx & 7) * 8) = v;
  }
}

// ---------------- combine: out[t] = sum_k wslot * (partA[row] + partB[row]) ----------------
__global__ void combine_k(const f16* __restrict__ pA, const f16* __restrict__ pB,
                          const int* __restrict__ eidx, const int* __restrict__ posa,
                          const float* __restrict__ wslot, float* __restrict__ out) {
  const int t = blockIdx.x, tid = threadIdx.x;
  const int s0 = 2 * t, s1 = 2 * t + 1;
  const int e0 = eidx[s0], e1 = eidx[s1];
  int p0 = posa[s0]; p0 = p0 < CAPD - 1 ? p0 : CAPD - 1;
  int p1 = posa[s1]; p1 = p1 < CAPD - 1 ? p1 : CAPD - 1;
  const float g0 = wslot[s0], g1 = wslot[s1];
  const size_t o0 = ((size_t)e0 * CAPD + p0) * DDIM;
  const size_t o1 = ((size_t)e1 * CAPD + p1) * DDIM;
  const f16x2* r0a = (const f16x2*)(pA + o0);
  const f16x2* r0b = (const f16x2*)(pB + o0);
  const f16x2* r1a = (const f16x2*)(pA + o1);
  const f16x2* r1b = (const f16x2*)(pB + o1);
  float2* o = (float2*)(out + (size_t)t * DDIM);
  #pragma unroll
  for (int j = tid; j < DDIM / 2; j += 256) {
    f16x2 a0 = r0a[j], a1 = r0b[j], b0 = r1a[j], b1 = r1b[j];
    o[j] = make_float2(
        g0 * ((float)a0.x + (float)a1.x) + g1 * ((float)b0.x + (float)b1.x),
        g0 * ((float)a0.y + (float)a1.y) + g1 * ((float)b0.y + (float)b1.y));
  }
}

extern "C" void kernel_launch(void* const* d_in, const int* in_sizes, int n_in,
                              void* d_out, int out_size, void* d_ws, size_t ws_size,
                              hipStream_t stream) {
  (void)in_sizes; (void)n_in; (void)out_size; (void)ws_size;
  const float* x  = (const float*)d_in[0];
  const float* rw = (const float*)d_in[1];
  const float* w1 = (const float*)d_in[2];
  const float* b1 = (const float*)d_in[3];
  const float* w2 = (const float*)d_in[4];
  const float* b2 = (const float*)d_in[5];
  float* out = (float*)d_out;

  char* ws = (char*)d_ws;
  size_t off = 0;
  auto alloc = [&](size_t b) { void* p = ws + off; off += (b + 255) & ~(size_t)255; return p; };
  f16* w1t   = (f16*)alloc((size_t)EDIM * DDIM * HDIM * 2);   // (E,H,D)
  f16* w2t   = (f16*)alloc((size_t)EDIM * DDIM * HDIM * 2);   // (E,D,H)
  f16* buf   = (f16*)alloc((size_t)EDIM * CAPD * DDIM * 2);   // (E,CAP,D)
  f16* hbuf  = (f16*)alloc((size_t)EDIM * CAPD * HDIM * 2);   // (E,CAP,H)
  const size_t PSTRIDE = (size_t)EDIM * CAPD * DDIM;
  f16* outeA = (f16*)alloc(PSTRIDE * 2);                       // split-K partial 0
  f16* outeB = (f16*)alloc(PSTRIDE * 2);                       // split-K partial 1 (contiguous)
  int*   eidx   = (int*)alloc(NSLOT * 4);
  int*   posa   = (int*)alloc(NSLOT * 4);
  float* gatesA = (float*)alloc(NSLOT * 4);
  float* wslotA = (float*)alloc(NSLOT * 4);
  int*   cc     = (int*)alloc(32 * EDIM * 4);
  int*   cb     = (int*)alloc(32 * EDIM * 4);
  int*   counts = (int*)alloc(EDIM * 4);
  int*   rowsN  = (int*)alloc(EDIM * 4);
  float* bps    = (float*)alloc(NROUTERBLK * EDIM * 4);
  (void)outeB;

  // weight conversion (independent of routing chain)
  transpose_cvt<<<dim3(HDIM / 64, DDIM / 64, EDIM), 256, 0, stream>>>(w1, w1t, DDIM, HDIM);
  transpose_cvt<<<dim3(DDIM / 64, HDIM / 64, EDIM), 256, 0, stream>>>(w2, w2t, HDIM, DDIM);

  // routing chain
  router_k<<<NROUTERBLK, 256, 0, stream>>>(x, rw, eidx, gatesA, bps);
  count_k<<<32, 256, 0, stream>>>(eidx, cc);
  scan_k<<<1, 256, 0, stream>>>(cc, bps, cb, counts, rowsN, out + (size_t)TDIM * DDIM);
  pos_k<<<32, 256, 0, stream>>>(eidx, gatesA, cb, posa, wslotA);
  scatter_k<<<NSLOT, 64, 0, stream>>>(x, eidx, posa, buf);

  // expert GEMM 1: (E,CAP,D) x (E,D,H) -> GELU -> (E,CAP,H)
  gemm256p<DDIM, DDIM, HDIM, 1, 16, 1><<<1024, 512, 0, stream>>>(
      buf, w1t, b1, hbuf, 0, rowsN);

  // expert GEMM 2, split-K=2 in ONE dispatch: wg = e + 8*(nt + 4*(ks + 2*mt))
  gemm256p<HDIM / 2, HDIM, DDIM, 0, 4, 2><<<512, 512, 0, stream>>>(
      hbuf, w2t, b2, outeA, PSTRIDE, rowsN);

  // combine
  combine_k<<<TDIM, 256, 0, stream>>>(outeA, outeA + PSTRIDE, eidx, posa, wslotA, out);

  // ---- DIAGNOSTIC dispatches (2x K-work, scratch output = hbuf, consumed above) ----
  // VAR=1: no in-loop staging/vmcnt -> isolates staging cost.
  // VAR=2: + no in-loop ds_reads -> barrier+MFMA floor.
  gemm256p<2 * DDIM, DDIM, HDIM, 1, 16, 1, 1><<<1024, 512, 0, stream>>>(
      buf, w1t, b1, hbuf, 0, rowsN);
  gemm256p<2 * DDIM, DDIM, HDIM, 1, 16, 1, 2><<<1024, 512, 0, stream>>>(
      buf, w1t, b1, hbuf, 0, rowsN);
}

// Round 10
// 339.483 us; speedup vs baseline: 1.8818x; 1.8818x over previous
//
#include <hip/hip_runtime.h>
#include <cstdint>
#include <cstddef>

#define TDIM 4096       // B*S tokens
#define DDIM 1024
#define HDIM 4096
#define EDIM 8
#define CAPD 2048
#define NSLOT 8192      // T*K
#define NROUTERBLK 1024

typedef _Float16 f16;
typedef _Float16 f16x2 __attribute__((ext_vector_type(2)));
typedef _Float16 f16x4 __attribute__((ext_vector_type(4)));
typedef _Float16 f16x8 __attribute__((ext_vector_type(8)));
typedef float f32x4 __attribute__((ext_vector_type(4)));

__device__ __forceinline__ void gload16(const void* g, void* l) {
  __builtin_amdgcn_global_load_lds(
      (const __attribute__((address_space(1))) unsigned int*)g,
      (__attribute__((address_space(3))) unsigned int*)l, 16, 0, 0);
}

__device__ __forceinline__ float gelu_fast(float x) {
  float y = 1.5957691216057308f * (x + 0.044715f * x * x * x);
  y = fminf(y, 60.f);
  float e = __expf(y);
  return x * e * __builtin_amdgcn_rcpf(e + 1.f);
}

#define MEMFENCE asm volatile("" ::: "memory")
#define VMCNT(n) asm volatile("s_waitcnt vmcnt(" #n ")" ::: "memory")
#define BAR do { MEMFENCE; __builtin_amdgcn_s_barrier(); MEMFENCE; } while (0)

// ---------------- transpose + f32->f16 convert: src (E,R,C) -> dst (E,C,R) ----------------
__global__ __launch_bounds__(256)
void transpose_cvt(const float* __restrict__ src, f16* __restrict__ dst, int R, int C) {
  __shared__ float tile[64][65];
  const int e = blockIdx.z;
  const int c0 = blockIdx.x * 64, r0 = blockIdx.y * 64;
  const int tid = threadIdx.x;
  const float* s = src + (size_t)e * R * C;
  f16* d = dst + (size_t)e * R * C;
  #pragma unroll
  for (int p = 0; p < 4; ++p) {
    const int row = p * 16 + (tid >> 4);
    const int col = (tid & 15) * 4;
    float4 v = *(const float4*)(s + (size_t)(r0 + row) * C + c0 + col);
    tile[row][col] = v.x; tile[row][col + 1] = v.y;
    tile[row][col + 2] = v.z; tile[row][col + 3] = v.w;
  }
  __syncthreads();
  #pragma unroll
  for (int p = 0; p < 4; ++p) {
    const int crow = p * 16 + (tid >> 4);
    const int q = (tid & 15) * 4;
    f16x4 o;
    #pragma unroll
    for (int j = 0; j < 4; ++j) o[j] = (f16)tile[q + j][crow];
    *(f16x4*)(d + (size_t)(c0 + crow) * R + r0 + q) = o;
  }
}

// ---------------- router ----------------
__global__ void router_k(const float* __restrict__ x, const float* __restrict__ rw,
                         int* __restrict__ eidx, float* __restrict__ gates,
                         float* __restrict__ bps) {
  __shared__ float lrw[EDIM * DDIM];
  __shared__ float wps[4][EDIM];
  const int tid = threadIdx.x, lane = tid & 63, wv = tid >> 6;
  for (int i = tid; i < EDIM * DDIM; i += 256) lrw[i] = rw[i];
  __syncthreads();
  const int t = blockIdx.x * 4 + wv;
  float acc[EDIM];
  #pragma unroll
  for (int e = 0; e < EDIM; ++e) acc[e] = 0.f;
  const float* xr = x + (size_t)t * DDIM;
  #pragma unroll
  for (int j = 0; j < DDIM / 64; ++j) {
    float xv = xr[j * 64 + lane];
    #pragma unroll
    for (int e = 0; e < EDIM; ++e) acc[e] += xv * lrw[e * DDIM + j * 64 + lane];
  }
  #pragma unroll
  for (int off = 32; off >= 1; off >>= 1) {
    #pragma unroll
    for (int e = 0; e < EDIM; ++e) acc[e] += __shfl_xor(acc[e], off);
  }
  float mx = acc[0];
  #pragma unroll
  for (int e = 1; e < EDIM; ++e) mx = fmaxf(mx, acc[e]);
  float p[EDIM], s = 0.f;
  #pragma unroll
  for (int e = 0; e < EDIM; ++e) { p[e] = expf(acc[e] - mx); s += p[e]; }
  float inv = 1.f / s;
  #pragma unroll
  for (int e = 0; e < EDIM; ++e) p[e] *= inv;
  int i1 = 0; float p1 = p[0];
  #pragma unroll
  for (int e = 1; e < EDIM; ++e) if (p[e] > p1) { p1 = p[e]; i1 = e; }
  int i2 = (i1 == 0) ? 1 : 0; float p2 = p[i2];
  #pragma unroll
  for (int e = 0; e < EDIM; ++e) if (e != i1 && p[e] > p2) { p2 = p[e]; i2 = e; }
  float gs = 1.f / (p1 + p2);
  if (lane == 0) {
    eidx[2 * t] = i1; eidx[2 * t + 1] = i2;
    gates[2 * t] = p1 * gs; gates[2 * t + 1] = p2 * gs;
    #pragma unroll
    for (int e = 0; e < EDIM; ++e) wps[wv][e] = p[e];
  }
  __syncthreads();
  if (tid < EDIM)
    bps[blockIdx.x * EDIM + tid] = wps[0][tid] + wps[1][tid] + wps[2][tid] + wps[3][tid];
}

// ---------------- per-chunk expert histogram ----------------
__global__ void count_k(const int* __restrict__ eidx, int* __restrict__ cc) {
  __shared__ int h[EDIM];
  const int tid = threadIdx.x;
  if (tid < EDIM) h[tid] = 0;
  __syncthreads();
  atomicAdd(&h[eidx[blockIdx.x * 256 + tid]], 1);
  __syncthreads();
  if (tid < EDIM) cc[blockIdx.x * EDIM + tid] = h[tid];
}

// ---------------- scan chunks, totals, lb_loss ----------------
__global__ void scan_k(const int* __restrict__ cc, const float* __restrict__ bps,
                       int* __restrict__ cb, int* __restrict__ counts,
                       int* __restrict__ rowsNeeded, float* __restrict__ lb_out) {
  __shared__ float red[32][EDIM];
  __shared__ int cnt_s[EDIM];
  const int tid = threadIdx.x;
  const int e = tid & 7, g = tid >> 3;
  float s = 0.f;
  for (int j = 0; j < 32; ++j) s += bps[(g + 32 * j) * EDIM + e];
  red[g][e] = s;
  __syncthreads();
  for (int st = 16; st >= 1; st >>= 1) {
    if (g < st) red[g][e] += red[g + st][e];
    __syncthreads();
  }
  if (tid < EDIM) {
    int base = 0;
    for (int c = 0; c < 32; ++c) { cb[c * EDIM + tid] = base; base += cc[c * EDIM + tid]; }
    counts[tid] = base;
    rowsNeeded[tid] = base < CAPD ? base : CAPD;
    cnt_s[tid] = base;
  }
  __syncthreads();
  if (tid == 0) {
    float lb = 0.f;
    for (int ee = 0; ee < EDIM; ++ee)
      lb += (red[0][ee] / (float)TDIM) * ((float)cnt_s[ee] / (float)NSLOT);
    lb_out[0] = lb * (float)EDIM;
  }
}

// ---------------- per-slot position via wave ballots (deterministic) ----------------
__global__ void pos_k(const int* __restrict__ eidx, const float* __restrict__ gates,
                      const int* __restrict__ cb, int* __restrict__ posa,
                      float* __restrict__ wslot) {
  __shared__ int wcnt[4][EDIM];
  const int tid = threadIdx.x, lane = tid & 63, wv = tid >> 6;
  const int slot = blockIdx.x * 256 + tid;
  const int e = eidx[slot];
  const unsigned long long below = (1ull << lane) - 1ull;
  int wavepos = 0;
  #pragma unroll
  for (int ee = 0; ee < EDIM; ++ee) {
    unsigned long long m = __ballot(e == ee);
    if (lane == 0) wcnt[wv][ee] = __popcll(m);
    if (e == ee) wavepos = __popcll(m & below);
  }
  __syncthreads();
  int off = 0;
  for (int w = 0; w < wv; ++w) off += wcnt[w][e];
  const int pos = cb[blockIdx.x * EDIM + e] + off + wavepos;
  posa[slot] = pos;
  wslot[slot] = (pos < CAPD) ? gates[slot] : 0.f;
}

// ---------------- scatter token rows -> f16 expert buffers ----------------
__global__ void scatter_k(const float* __restrict__ x, const int* __restrict__ eidx,
                          const int* __restrict__ posa, f16* __restrict__ buf) {
  const int s = blockIdx.x, lane = threadIdx.x;
  const int p = posa[s];
  if (p >= CAPD) return;
  const int e = eidx[s], tok = s >> 1;
  const float4* src = (const float4*)(x + (size_t)tok * DDIM);
  f16x4* dst = (f16x4*)(buf + ((size_t)e * CAPD + p) * DDIM);
  #pragma unroll
  for (int j = 0; j < DDIM / 4 / 64; ++j) {
    float4 v = src[j * 64 + lane];
    f16x4 o; o.x = (f16)v.x; o.y = (f16)v.y; o.z = (f16)v.z; o.w = (f16)v.w;
    dst[j * 64 + lane] = o;
  }
}

// ============ 256x256 f16 MFMA GEMM — MINIMAL-BARRIER K-loop (r10) ============
// r9 ablation: ds_reads free, staging 24%, barrier skeleton 76%. So: ONE barrier +
// ONE vmcnt per K-tile. Per tile: {STAGE(t+1 -> alt); ds_read frags(cur); 64 MFMA
// (compiler emits counted lgkmcnt -> reads overlap MFMA); VMCNT(0) (stage issued a
// full tile earlier -> drain free); BAR}. alt-overwrite safe: t-1's readers finished
// before previous BAR. Dbuf layout per buffer (64KB): A0|A1|B0|B1 16KB quarters.
// hh2: 0=A rows0-127, 1=A rows128-255, 2=B rows0-127, 3=B rows128-255
#define STAGE(bb, hh2, g) do { \
    const f16* s_ = sP[hh2] + (g) * 64; \
    char* d_ = smem + (bb) * 65536 + (hh2) * 16384 + wv * 1024; \
    gload16(s_, d_); \
    gload16(s_ + (size_t)64 * LD, d_ + 8192); \
  } while (0)

template<int KLEN, int LD, int N, int GELU, int NT, int NKS>
__global__ __launch_bounds__(512, 1)
void gemm256s(const f16* __restrict__ A, const f16* __restrict__ Bt,
              const float* __restrict__ bias, f16* __restrict__ C, size_t pstride,
              const int* __restrict__ rowsNeeded) {
  constexpr int NTT = KLEN / 64;           // K-tiles
  __shared__ __align__(128) char smem[131072];
  const int wg = blockIdx.x;
  const int e = wg & 7;
  const int r = wg >> 3;
  const int nt = r % NT;
  const int ks = (r / NT) % NKS;
  const int mt = r / (NT * NKS);
  if (mt * 256 >= rowsNeeded[e]) return;
  const int tid = threadIdx.x, lane = tid & 63, wv = tid >> 6;
  const int wr = wv >> 2, wc = wv & 3;     // 2 x 4 wave grid
  const int ro = lane & 15, q4 = (lane >> 4) * 4;
  const int ko0b = (lane >> 4) * 16;       // k-offset bytes within row
  const f16* aBase = A + ((size_t)e * CAPD + (size_t)mt * 256) * LD + (size_t)ks * KLEN;
  const f16* bBase = Bt + ((size_t)e * N + (size_t)nt * 256) * LD + (size_t)ks * KLEN;
  const int row0 = tid >> 3;               // 0..63 (second gload does row0+64)
  const int sw0 = ((tid & 7) ^ (row0 & 7)) * 8;   // pre-swizzled source col (elements)

  // hoisted global staging bases (per hh2)
  const f16* sP[4];
  sP[0] = aBase + (size_t)row0 * LD + sw0;
  sP[1] = sP[0] + (size_t)128 * LD;
  sP[2] = bBase + (size_t)row0 * LD + sw0;
  sP[3] = sP[2] + (size_t)128 * LD;

  // hoisted LDS read byte-offsets for buffer 0 (+ cur*65536 at use; +8192 for A mh1,
  // +4096 for B n-half 1 fold into ds_read immediates)
  int aoffs[4][2], boffs[2][2];
  #pragma unroll
  for (int m = 0; m < 4; ++m)
    #pragma unroll
    for (int k = 0; k < 2; ++k) {
      const int rh = m * 16 + ro;
      aoffs[m][k] = wr * 16384 + rh * 128 + ((k * 64 + ko0b) ^ ((rh & 7) << 4));
    }
  #pragma unroll
  for (int n = 0; n < 2; ++n)
    #pragma unroll
    for (int k = 0; k < 2; ++k) {
      const int rh = (wc & 1) * 64 + n * 16 + ro;
      boffs[n][k] = (2 + (wc >> 1)) * 16384 + rh * 128 + ((k * 64 + ko0b) ^ ((rh & 7) << 4));
    }

  f32x4 acc[8][4];
  #pragma unroll
  for (int m = 0; m < 8; ++m)
    #pragma unroll
    for (int n = 0; n < 4; ++n) acc[m][n] = (f32x4){0.f, 0.f, 0.f, 0.f};

  // ---- prologue: stage tile 0 into buf0
  STAGE(0, 0, 0); STAGE(0, 1, 0); STAGE(0, 2, 0); STAGE(0, 3, 0);
  VMCNT(0);
  BAR;

  #pragma unroll 1
  for (int t = 0; t < NTT; ++t) {
    const int cur = t & 1;
    const int cb = cur << 16;
    if (t + 1 < NTT) {                     // stage next tile into the freed buffer
      const int ab = cur ^ 1;
      STAGE(ab, 0, t + 1); STAGE(ab, 1, t + 1);
      STAGE(ab, 2, t + 1); STAGE(ab, 3, t + 1);
    }
    f16x8 af[4][2], bf[4][2];
    #pragma unroll
    for (int n = 0; n < 4; ++n)
      #pragma unroll
      for (int k = 0; k < 2; ++k)
        bf[n][k] = *(const f16x8*)(smem + cb + boffs[n & 1][k] + (n >> 1) * 4096);
    #pragma unroll
    for (int m = 0; m < 4; ++m)
      #pragma unroll
      for (int k = 0; k < 2; ++k)
        af[m][k] = *(const f16x8*)(smem + cb + aoffs[m][k]);
    __builtin_amdgcn_s_setprio(1);
    #pragma unroll
    for (int m = 0; m < 4; ++m)
      #pragma unroll
      for (int n = 0; n < 4; ++n)
        #pragma unroll
        for (int k = 0; k < 2; ++k)
          acc[m][n] = __builtin_amdgcn_mfma_f32_16x16x32_f16(af[m][k], bf[n][k], acc[m][n], 0, 0, 0);
    __builtin_amdgcn_s_setprio(0);
    #pragma unroll
    for (int m = 0; m < 4; ++m)
      #pragma unroll
      for (int k = 0; k < 2; ++k)
        af[m][k] = *(const f16x8*)(smem + cb + aoffs[m][k] + 8192);
    __builtin_amdgcn_s_setprio(1);
    #pragma unroll
    for (int m = 0; m < 4; ++m)
      #pragma unroll
      for (int n = 0; n < 4; ++n)
        #pragma unroll
        for (int k = 0; k < 2; ++k)
          acc[4 + m][n] = __builtin_amdgcn_mfma_f32_16x16x32_f16(af[m][k], bf[n][k], acc[4 + m][n], 0, 0, 0);
    __builtin_amdgcn_s_setprio(0);
    if (t + 1 < NTT) VMCNT(0);             // next tile's 8 loads landed (issued ~1 tile ago)
    BAR;                                   // visibility + protects buffers from overwrite
  }

  // ---- epilogue: per-wave 16KB LDS region, swizzled conflict-free, coalesced stores
  float bv[4];
  #pragma unroll
  for (int n = 0; n < 4; ++n)
    bv[n] = (ks == 0) ? bias[e * N + nt * 256 + wc * 64 + n * 16 + ro] : 0.f;
  f16* Ct = (f16*)(smem + wv * 16384);      // [128][64] f16, col-byte ^= ((row>>2)&3)<<5
  #pragma unroll
  for (int m = 0; m < 8; ++m)
    #pragma unroll
    for (int n = 0; n < 4; ++n)
      #pragma unroll
      for (int i = 0; i < 4; ++i) {
        const int row = m * 16 + q4 + i;
        float v = acc[m][n][i] + bv[n];
        if (GELU) v = gelu_fast(v);
        *(f16*)((char*)Ct + row * 128 + ((((n * 16 + ro) * 2)) ^ (((row >> 2) & 3) << 5))) = (f16)v;
      }
  asm volatile("s_waitcnt lgkmcnt(0)" ::: "memory");
  f16* Cp = C + (size_t)ks * pstride;
  const size_t crow0 = (size_t)e * CAPD + mt * 256 + wr * 128;
  const int ccol0 = nt * 256 + wc * 64;
  #pragma unroll
  for (int j = 0; j < 16; ++j) {
    const int idx = j * 64 + lane;
    const int rr = idx >> 3, c2 = (idx & 7) * 16;
    f16x8 v = *(const f16x8*)((const char*)Ct + rr * 128 + (c2 ^ (((rr >> 2) & 3) << 5)));
    *(f16x8*)(Cp + (crow0 + rr) * N + ccol0 + (idx & 7) * 8) = v;
  }
}

// ---------------- combine: out[t] = sum_k wslot * (partA[row] + partB[row]) ----------------
__global__ void combine_k(const f16* __restrict__ pA, const f16* __restrict__ pB,
                          const int* __restrict__ eidx, const int* __restrict__ posa,
                          const float* __restrict__ wslot, float* __restrict__ out) {
  const int t = blockIdx.x, tid = threadIdx.x;
  const int s0 = 2 * t, s1 = 2 * t + 1;
  const int e0 = eidx[s0], e1 = eidx[s1];
  int p0 = posa[s0]; p0 = p0 < CAPD - 1 ? p0 : CAPD - 1;
  int p1 = posa[s1]; p1 = p1 < CAPD - 1 ? p1 : CAPD - 1;
  const float g0 = wslot[s0], g1 = wslot[s1];
  const size_t o0 = ((size_t)e0 * CAPD + p0) * DDIM;
  const size_t o1 = ((size_t)e1 * CAPD + p1) * DDIM;
  const f16x2* r0a = (const f16x2*)(pA + o0);
  const f16x2* r0b = (const f16x2*)(pB + o0);
  const f16x2* r1a = (const f16x2*)(pA + o1);
  const f16x2* r1b = (const f16x2*)(pB + o1);
  float2* o = (float2*)(out + (size_t)t * DDIM);
  #pragma unroll
  for (int j = tid; j < DDIM / 2; j += 256) {
    f16x2 a0 = r0a[j], a1 = r0b[j], b0 = r1a[j], b1 = r1b[j];
    o[j] = make_float2(
        g0 * ((float)a0.x + (float)a1.x) + g1 * ((float)b0.x + (float)b1.x),
        g0 * ((float)a0.y + (float)a1.y) + g1 * ((float)b0.y + (float)b1.y));
  }
}

extern "C" void kernel_launch(void* const* d_in, const int* in_sizes, int n_in,
                              void* d_out, int out_size, void* d_ws, size_t ws_size,
                              hipStream_t stream) {
  (void)in_sizes; (void)n_in; (void)out_size; (void)ws_size;
  const float* x  = (const float*)d_in[0];
  const float* rw = (const float*)d_in[1];
  const float* w1 = (const float*)d_in[2];
  const float* b1 = (const float*)d_in[3];
  const float* w2 = (const float*)d_in[4];
  const float* b2 = (const float*)d_in[5];
  float* out = (float*)d_out;

  char* ws = (char*)d_ws;
  size_t off = 0;
  auto alloc = [&](size_t b) { void* p = ws + off; off += (b + 255) & ~(size_t)255; return p; };
  f16* w1t   = (f16*)alloc((size_t)EDIM * DDIM * HDIM * 2);   // (E,H,D)
  f16* w2t   = (f16*)alloc((size_t)EDIM * DDIM * HDIM * 2);   // (E,D,H)
  f16* buf   = (f16*)alloc((size_t)EDIM * CAPD * DDIM * 2);   // (E,CAP,D)
  f16* hbuf  = (f16*)alloc((size_t)EDIM * CAPD * HDIM * 2);   // (E,CAP,H)
  const size_t PSTRIDE = (size_t)EDIM * CAPD * DDIM;
  f16* outeA = (f16*)alloc(PSTRIDE * 2);                       // split-K partial 0
  f16* outeB = (f16*)alloc(PSTRIDE * 2);                       // split-K partial 1 (contiguous)
  int*   eidx   = (int*)alloc(NSLOT * 4);
  int*   posa   = (int*)alloc(NSLOT * 4);
  float* gatesA = (float*)alloc(NSLOT * 4);
  float* wslotA = (float*)alloc(NSLOT * 4);
  int*   cc     = (int*)alloc(32 * EDIM * 4);
  int*   cb     = (int*)alloc(32 * EDIM * 4);
  int*   counts = (int*)alloc(EDIM * 4);
  int*   rowsN  = (int*)alloc(EDIM * 4);
  float* bps    = (float*)alloc(NROUTERBLK * EDIM * 4);
  (void)outeB;

  // weight conversion (independent of routing chain)
  transpose_cvt<<<dim3(HDIM / 64, DDIM / 64, EDIM), 256, 0, stream>>>(w1, w1t, DDIM, HDIM);
  transpose_cvt<<<dim3(DDIM / 64, HDIM / 64, EDIM), 256, 0, stream>>>(w2, w2t, HDIM, DDIM);

  // routing chain
  router_k<<<NROUTERBLK, 256, 0, stream>>>(x, rw, eidx, gatesA, bps);
  count_k<<<32, 256, 0, stream>>>(eidx, cc);
  scan_k<<<1, 256, 0, stream>>>(cc, bps, cb, counts, rowsN, out + (size_t)TDIM * DDIM);
  pos_k<<<32, 256, 0, stream>>>(eidx, gatesA, cb, posa, wslotA);
  scatter_k<<<NSLOT, 64, 0, stream>>>(x, eidx, posa, buf);

  // expert GEMM 1: (E,CAP,D) x (E,D,H) -> GELU -> (E,CAP,H)
  // 1-D grid: wg = e + 8*(nt + 16*mt)  (e fastest -> XCD-affine; mt slowest)
  gemm256s<DDIM, DDIM, HDIM, 1, 16, 1><<<1024, 512, 0, stream>>>(
      buf, w1t, b1, hbuf, 0, rowsN);

  // expert GEMM 2, split-K=2 in ONE dispatch: wg = e + 8*(nt + 4*(ks + 2*mt))
  gemm256s<HDIM / 2, HDIM, DDIM, 0, 4, 2><<<512, 512, 0, stream>>>(
      hbuf, w2t, b2, outeA, PSTRIDE, rowsN);

  // combine
  combine_k<<<TDIM, 256, 0, stream>>>(outeA, outeA + PSTRIDE, eidx, posa, wslotA, out);
}

// Round 12
// 318.476 us; speedup vs baseline: 2.0059x; 1.0660x over previous
//
#include <hip/hip_runtime.h>
#include <cstdint>
#include <cstddef>

#define TDIM 4096       // B*S tokens
#define DDIM 1024
#define HDIM 4096
#define EDIM 8
#define CAPD 2048
#define NSLOT 8192      // T*K
#define NROUTERBLK 1024

typedef _Float16 f16;
typedef _Float16 f16x2 __attribute__((ext_vector_type(2)));
typedef _Float16 f16x4 __attribute__((ext_vector_type(4)));
typedef _Float16 f16x8 __attribute__((ext_vector_type(8)));
typedef float f32x4 __attribute__((ext_vector_type(4)));

__device__ __forceinline__ void gload16(const void* g, void* l) {
  __builtin_amdgcn_global_load_lds(
      (const __attribute__((address_space(1))) unsigned int*)g,
      (__attribute__((address_space(3))) unsigned int*)l, 16, 0, 0);
}

__device__ __forceinline__ float gelu_fast(float x) {
  float y = 1.5957691216057308f * (x + 0.044715f * x * x * x);
  y = fminf(y, 60.f);
  float e = __expf(y);
  return x * e * __builtin_amdgcn_rcpf(e + 1.f);
}

#define MEMFENCE asm volatile("" ::: "memory")

// ---------------- transpose + f32->f16 convert: src (E,R,C) -> dst (E,C,R) ----------------
__global__ __launch_bounds__(256)
void transpose_cvt(const float* __restrict__ src, f16* __restrict__ dst, int R, int C) {
  __shared__ float tile[64][65];
  const int e = blockIdx.z;
  const int c0 = blockIdx.x * 64, r0 = blockIdx.y * 64;
  const int tid = threadIdx.x;
  const float* s = src + (size_t)e * R * C;
  f16* d = dst + (size_t)e * R * C;
  #pragma unroll
  for (int p = 0; p < 4; ++p) {
    const int row = p * 16 + (tid >> 4);
    const int col = (tid & 15) * 4;
    float4 v = *(const float4*)(s + (size_t)(r0 + row) * C + c0 + col);
    tile[row][col] = v.x; tile[row][col + 1] = v.y;
    tile[row][col + 2] = v.z; tile[row][col + 3] = v.w;
  }
  __syncthreads();
  #pragma unroll
  for (int p = 0; p < 4; ++p) {
    const int crow = p * 16 + (tid >> 4);
    const int q = (tid & 15) * 4;
    f16x4 o;
    #pragma unroll
    for (int j = 0; j < 4; ++j) o[j] = (f16)tile[q + j][crow];
    *(f16x4*)(d + (size_t)(c0 + crow) * R + r0 + q) = o;
  }
}

// ---------------- router ----------------
__global__ void router_k(const float* __restrict__ x, const float* __restrict__ rw,
                         int* __restrict__ eidx, float* __restrict__ gates,
                         float* __restrict__ bps) {
  __shared__ float lrw[EDIM * DDIM];
  __shared__ float wps[4][EDIM];
  const int tid = threadIdx.x, lane = tid & 63, wv = tid >> 6;
  for (int i = tid; i < EDIM * DDIM; i += 256) lrw[i] = rw[i];
  __syncthreads();
  const int t = blockIdx.x * 4 + wv;
  float acc[EDIM];
  #pragma unroll
  for (int e = 0; e < EDIM; ++e) acc[e] = 0.f;
  const float* xr = x + (size_t)t * DDIM;
  #pragma unroll
  for (int j = 0; j < DDIM / 64; ++j) {
    float xv = xr[j * 64 + lane];
    #pragma unroll
    for (int e = 0; e < EDIM; ++e) acc[e] += xv * lrw[e * DDIM + j * 64 + lane];
  }
  #pragma unroll
  for (int off = 32; off >= 1; off >>= 1) {
    #pragma unroll
    for (int e = 0; e < EDIM; ++e) acc[e] += __shfl_xor(acc[e], off);
  }
  float mx = acc[0];
  #pragma unroll
  for (int e = 1; e < EDIM; ++e) mx = fmaxf(mx, acc[e]);
  float p[EDIM], s = 0.f;
  #pragma unroll
  for (int e = 0; e < EDIM; ++e) { p[e] = expf(acc[e] - mx); s += p[e]; }
  float inv = 1.f / s;
  #pragma unroll
  for (int e = 0; e < EDIM; ++e) p[e] *= inv;
  int i1 = 0; float p1 = p[0];
  #pragma unroll
  for (int e = 1; e < EDIM; ++e) if (p[e] > p1) { p1 = p[e]; i1 = e; }
  int i2 = (i1 == 0) ? 1 : 0; float p2 = p[i2];
  #pragma unroll
  for (int e = 0; e < EDIM; ++e) if (e != i1 && p[e] > p2) { p2 = p[e]; i2 = e; }
  float gs = 1.f / (p1 + p2);
  if (lane == 0) {
    eidx[2 * t] = i1; eidx[2 * t + 1] = i2;
    gates[2 * t] = p1 * gs; gates[2 * t + 1] = p2 * gs;
    #pragma unroll
    for (int e = 0; e < EDIM; ++e) wps[wv][e] = p[e];
  }
  __syncthreads();
  if (tid < EDIM)
    bps[blockIdx.x * EDIM + tid] = wps[0][tid] + wps[1][tid] + wps[2][tid] + wps[3][tid];
}

// ---------------- per-chunk expert histogram ----------------
__global__ void count_k(const int* __restrict__ eidx, int* __restrict__ cc) {
  __shared__ int h[EDIM];
  const int tid = threadIdx.x;
  if (tid < EDIM) h[tid] = 0;
  __syncthreads();
  atomicAdd(&h[eidx[blockIdx.x * 256 + tid]], 1);
  __syncthreads();
  if (tid < EDIM) cc[blockIdx.x * EDIM + tid] = h[tid];
}

// ---------------- scan chunks, totals, lb_loss ----------------
__global__ void scan_k(const int* __restrict__ cc, const float* __restrict__ bps,
                       int* __restrict__ cb, int* __restrict__ counts,
                       int* __restrict__ rowsNeeded, float* __restrict__ lb_out) {
  __shared__ float red[32][EDIM];
  __shared__ int cnt_s[EDIM];
  const int tid = threadIdx.x;
  const int e = tid & 7, g = tid >> 3;
  float s = 0.f;
  for (int j = 0; j < 32; ++j) s += bps[(g + 32 * j) * EDIM + e];
  red[g][e] = s;
  __syncthreads();
  for (int st = 16; st >= 1; st >>= 1) {
    if (g < st) red[g][e] += red[g + st][e];
    __syncthreads();
  }
  if (tid < EDIM) {
    int base = 0;
    for (int c = 0; c < 32; ++c) { cb[c * EDIM + tid] = base; base += cc[c * EDIM + tid]; }
    counts[tid] = base;
    rowsNeeded[tid] = base < CAPD ? base : CAPD;
    cnt_s[tid] = base;
  }
  __syncthreads();
  if (tid == 0) {
    float lb = 0.f;
    for (int ee = 0; ee < EDIM; ++ee)
      lb += (red[0][ee] / (float)TDIM) * ((float)cnt_s[ee] / (float)NSLOT);
    lb_out[0] = lb * (float)EDIM;
  }
}

// ---------------- per-slot position via wave ballots (deterministic) ----------------
__global__ void pos_k(const int* __restrict__ eidx, const float* __restrict__ gates,
                      const int* __restrict__ cb, int* __restrict__ posa,
                      float* __restrict__ wslot) {
  __shared__ int wcnt[4][EDIM];
  const int tid = threadIdx.x, lane = tid & 63, wv = tid >> 6;
  const int slot = blockIdx.x * 256 + tid;
  const int e = eidx[slot];
  const unsigned long long below = (1ull << lane) - 1ull;
  int wavepos = 0;
  #pragma unroll
  for (int ee = 0; ee < EDIM; ++ee) {
    unsigned long long m = __ballot(e == ee);
    if (lane == 0) wcnt[wv][ee] = __popcll(m);
    if (e == ee) wavepos = __popcll(m & below);
  }
  __syncthreads();
  int off = 0;
  for (int w = 0; w < wv; ++w) off += wcnt[w][e];
  const int pos = cb[blockIdx.x * EDIM + e] + off + wavepos;
  posa[slot] = pos;
  wslot[slot] = (pos < CAPD) ? gates[slot] : 0.f;
}

// ---------------- scatter token rows -> f16 expert buffers ----------------
__global__ void scatter_k(const float* __restrict__ x, const int* __restrict__ eidx,
                          const int* __restrict__ posa, f16* __restrict__ buf) {
  const int s = blockIdx.x, lane = threadIdx.x;
  const int p = posa[s];
  if (p >= CAPD) return;
  const int e = eidx[s], tok = s >> 1;
  const float4* src = (const float4*)(x + (size_t)tok * DDIM);
  f16x4* dst = (f16x4*)(buf + ((size_t)e * CAPD + p) * DDIM);
  #pragma unroll
  for (int j = 0; j < DDIM / 4 / 64; ++j) {
    float4 v = src[j * 64 + lane];
    f16x4 o; o.x = (f16)v.x; o.y = (f16)v.y; o.z = (f16)v.z; o.w = (f16)v.w;
    dst[j * 64 + lane] = o;
  }
}

// ============ 128x128 f16 MFMA GEMM — m97/m103 structure, 2 blocks/CU (r12) ============
// r9-r11 established: at 1 block/CU every skeleton stall is exposed (3.7x MFMA floor);
// m103 shows the same drain-style loop reaches 912 TF with 2-3 resident blocks/CU
// (block-level overlap hides barrier/stage stalls). 64KB LDS -> 2 blocks/CU resident.
// Race-hardening (r11 lesson, rule #18): every K-loop barrier is preceded by
// lgkmcnt(0)+vmcnt(0) drains and sched_barrier(0) so no in-flight LDS reads can cross.
// Buffer layout (32KB each): A rows0-127 (16KB) | B rows0-127 (16KB).
// hh: 0=A rows0-63, 1=A rows64-127, 2=B rows0-63, 3=B rows64-127 (8KB quarters).
#define STAGE(bb, hh, g) do { \
    const f16* s_ = sP[hh] + (g) * 64; \
    char* d_ = smem + (bb) * 32768 + (hh) * 8192 + wv * 1024; \
    gload16(s_, d_); \
    gload16(s_ + (size_t)32 * LD, d_ + 4096); \
  } while (0)

template<int KLEN, int LD, int N, int GELU, int NT, int NKS>
__global__ __launch_bounds__(256, 2)
void gemm128(const f16* __restrict__ A, const f16* __restrict__ Bt,
             const float* __restrict__ bias, f16* __restrict__ C, size_t pstride,
             const int* __restrict__ rowsNeeded) {
  constexpr int NTT = KLEN / 64;           // K-tiles
  __shared__ __align__(128) char smem[65536];
  const int wg = blockIdx.x;
  const int e = wg & 7;
  const int r = wg >> 3;
  const int nt = r % NT;
  const int ks = (r / NT) % NKS;
  const int mt = r / (NT * NKS);
  if (mt * 128 >= rowsNeeded[e]) return;
  const int tid = threadIdx.x, lane = tid & 63, wv = tid >> 6;   // wv 0..3
  const int wr = wv >> 1, wc = wv & 1;     // 2 x 2 wave grid, per-wave 64x64 out
  const int ro = lane & 15, q4 = (lane >> 4) * 4;
  const int ko0b = (lane >> 4) * 16;       // k-offset bytes within 128B row
  const f16* aBase = A + ((size_t)e * CAPD + (size_t)mt * 128) * LD + (size_t)ks * KLEN;
  const f16* bBase = Bt + ((size_t)e * N + (size_t)nt * 128) * LD + (size_t)ks * KLEN;
  const int row0 = tid >> 3;               // 0..31 (second gload does row0+32)
  const int sw0 = ((tid & 7) ^ (row0 & 7)) * 8;   // pre-swizzled source col (elements)

  const f16* sP[4];
  sP[0] = aBase + (size_t)row0 * LD + sw0;
  sP[1] = sP[0] + (size_t)64 * LD;
  sP[2] = bBase + (size_t)row0 * LD + sw0;
  sP[3] = sP[2] + (size_t)64 * LD;

  // hoisted LDS read byte-offsets (buffer 0; + cur*32768 at use)
  int aoffs[4][2], boffs[4][2];
  #pragma unroll
  for (int m = 0; m < 4; ++m)
    #pragma unroll
    for (int k = 0; k < 2; ++k) {
      const int rh = wr * 64 + m * 16 + ro;
      aoffs[m][k] = rh * 128 + ((k * 64 + ko0b) ^ ((rh & 7) << 4));
      const int rb = wc * 64 + m * 16 + ro;
      boffs[m][k] = 16384 + rb * 128 + ((k * 64 + ko0b) ^ ((rb & 7) << 4));
    }

  f32x4 acc[4][4];
  #pragma unroll
  for (int m = 0; m < 4; ++m)
    #pragma unroll
    for (int n = 0; n < 4; ++n) acc[m][n] = (f32x4){0.f, 0.f, 0.f, 0.f};

  // ---- prologue: stage tile 0 into buf0
  STAGE(0, 0, 0); STAGE(0, 1, 0); STAGE(0, 2, 0); STAGE(0, 3, 0);
  asm volatile("s_waitcnt vmcnt(0)" ::: "memory");
  __builtin_amdgcn_sched_barrier(0);
  __builtin_amdgcn_s_barrier(); MEMFENCE;

  #pragma unroll 1
  for (int t = 0; t < NTT; ++t) {
    const int cb = (t & 1) << 15;
    if (t + 1 < NTT) {                     // stage next tile into the freed buffer
      const int ab = (t & 1) ^ 1;
      STAGE(ab, 0, t + 1); STAGE(ab, 1, t + 1);
      STAGE(ab, 2, t + 1); STAGE(ab, 3, t + 1);
    }
    f16x8 af[4][2], bf[4][2];
    #pragma unroll
    for (int m = 0; m < 4; ++m)
      #pragma unroll
      for (int k = 0; k < 2; ++k) {
        af[m][k] = *(const f16x8*)(smem + cb + aoffs[m][k]);
        bf[m][k] = *(const f16x8*)(smem + cb + boffs[m][k]);
      }
    #pragma unroll
    for (int k = 0; k < 2; ++k)
      #pragma unroll
      for (int m = 0; m < 4; ++m)
        #pragma unroll
        for (int n = 0; n < 4; ++n)
          acc[m][n] = __builtin_amdgcn_mfma_f32_16x16x32_f16(af[m][k], bf[n][k], acc[m][n], 0, 0, 0);
    // race-hardened tile boundary: drain my LDS reads + my stage loads, pin schedule
    asm volatile("s_waitcnt lgkmcnt(0)" ::: "memory");
    asm volatile("s_waitcnt vmcnt(0)" ::: "memory");
    __builtin_amdgcn_sched_barrier(0);
    __builtin_amdgcn_s_barrier(); MEMFENCE;
  }

  // ---- epilogue: per-wave 8KB LDS region, swizzled conflict-free, coalesced stores
  float bv[4];
  #pragma unroll
  for (int n = 0; n < 4; ++n)
    bv[n] = (ks == 0) ? bias[e * N + nt * 128 + wc * 64 + n * 16 + ro] : 0.f;
  f16* Ct = (f16*)(smem + wv * 8192);       // [64][64] f16, col-byte ^= ((row>>2)&3)<<5
  #pragma unroll
  for (int m = 0; m < 4; ++m)
    #pragma unroll
    for (int n = 0; n < 4; ++n)
      #pragma unroll
      for (int i = 0; i < 4; ++i) {
        const int row = m * 16 + q4 + i;
        float v = acc[m][n][i] + bv[n];
        if (GELU) v = gelu_fast(v);
        *(f16*)((char*)Ct + row * 128 + (((n * 16 + ro) * 2) ^ (((row >> 2) & 3) << 5))) = (f16)v;
      }
  asm volatile("s_waitcnt lgkmcnt(0)" ::: "memory");
  __builtin_amdgcn_sched_barrier(0);
  f16* Cp = C + (size_t)ks * pstride;
  const size_t crow0 = (size_t)e * CAPD + mt * 128 + wr * 64;
  const int ccol0 = nt * 128 + wc * 64;
  #pragma unroll
  for (int j = 0; j < 8; ++j) {
    const int idx = j * 64 + lane;
    const int rr = idx >> 3, c2 = (idx & 7) * 16;
    f16x8 v = *(const f16x8*)((const char*)Ct + rr * 128 + (c2 ^ (((rr >> 2) & 3) << 5)));
    *(f16x8*)(Cp + (crow0 + rr) * N + ccol0 + (idx & 7) * 8) = v;
  }
}

// ---------------- combine: out[t] = sum_k wslot * (partA[row] + partB[row]) ----------------
__global__ void combine_k(const f16* __restrict__ pA, const f16* __restrict__ pB,
                          const int* __restrict__ eidx, const int* __restrict__ posa,
                          const float* __restrict__ wslot, float* __restrict__ out) {
  const int t = blockIdx.x, tid = threadIdx.x;
  const int s0 = 2 * t, s1 = 2 * t + 1;
  const int e0 = eidx[s0], e1 = eidx[s1];
  int p0 = posa[s0]; p0 = p0 < CAPD - 1 ? p0 : CAPD - 1;
  int p1 = posa[s1]; p1 = p1 < CAPD - 1 ? p1 : CAPD - 1;
  const float g0 = wslot[s0], g1 = wslot[s1];
  const size_t o0 = ((size_t)e0 * CAPD + p0) * DDIM;
  const size_t o1 = ((size_t)e1 * CAPD + p1) * DDIM;
  const f16x2* r0a = (const f16x2*)(pA + o0);
  const f16x2* r0b = (const f16x2*)(pB + o0);
  const f16x2* r1a = (const f16x2*)(pA + o1);
  const f16x2* r1b = (const f16x2*)(pB + o1);
  float2* o = (float2*)(out + (size_t)t * DDIM);
  #pragma unroll
  for (int j = tid; j < DDIM / 2; j += 256) {
    f16x2 a0 = r0a[j], a1 = r0b[j], b0 = r1a[j], b1 = r1b[j];
    o[j] = make_float2(
        g0 * ((float)a0.x + (float)a1.x) + g1 * ((float)b0.x + (float)b1.x),
        g0 * ((float)a0.y + (float)a1.y) + g1 * ((float)b0.y + (float)b1.y));
  }
}

extern "C" void kernel_launch(void* const* d_in, const int* in_sizes, int n_in,
                              void* d_out, int out_size, void* d_ws, size_t ws_size,
                              hipStream_t stream) {
  (void)in_sizes; (void)n_in; (void)out_size; (void)ws_size;
  const float* x  = (const float*)d_in[0];
  const float* rw = (const float*)d_in[1];
  const float* w1 = (const float*)d_in[2];
  const float* b1 = (const float*)d_in[3];
  const float* w2 = (const float*)d_in[4];
  const float* b2 = (const float*)d_in[5];
  float* out = (float*)d_out;

  char* ws = (char*)d_ws;
  size_t off = 0;
  auto alloc = [&](size_t b) { void* p = ws + off; off += (b + 255) & ~(size_t)255; return p; };
  f16* w1t   = (f16*)alloc((size_t)EDIM * DDIM * HDIM * 2);   // (E,H,D)
  f16* w2t   = (f16*)alloc((size_t)EDIM * DDIM * HDIM * 2);   // (E,D,H)
  f16* buf   = (f16*)alloc((size_t)EDIM * CAPD * DDIM * 2);   // (E,CAP,D)
  f16* hbuf  = (f16*)alloc((size_t)EDIM * CAPD * HDIM * 2);   // (E,CAP,H)
  const size_t PSTRIDE = (size_t)EDIM * CAPD * DDIM;
  f16* outeA = (f16*)alloc(PSTRIDE * 2);                       // split-K partial 0
  f16* outeB = (f16*)alloc(PSTRIDE * 2);                       // split-K partial 1 (contiguous)
  int*   eidx   = (int*)alloc(NSLOT * 4);
  int*   posa   = (int*)alloc(NSLOT * 4);
  float* gatesA = (float*)alloc(NSLOT * 4);
  float* wslotA = (float*)alloc(NSLOT * 4);
  int*   cc     = (int*)alloc(32 * EDIM * 4);
  int*   cb     = (int*)alloc(32 * EDIM * 4);
  int*   counts = (int*)alloc(EDIM * 4);
  int*   rowsN  = (int*)alloc(EDIM * 4);
  float* bps    = (float*)alloc(NROUTERBLK * EDIM * 4);
  (void)outeB;

  // weight conversion (independent of routing chain)
  transpose_cvt<<<dim3(HDIM / 64, DDIM / 64, EDIM), 256, 0, stream>>>(w1, w1t, DDIM, HDIM);
  transpose_cvt<<<dim3(DDIM / 64, HDIM / 64, EDIM), 256, 0, stream>>>(w2, w2t, HDIM, DDIM);

  // routing chain
  router_k<<<NROUTERBLK, 256, 0, stream>>>(x, rw, eidx, gatesA, bps);
  count_k<<<32, 256, 0, stream>>>(eidx, cc);
  scan_k<<<1, 256, 0, stream>>>(cc, bps, cb, counts, rowsN, out + (size_t)TDIM * DDIM);
  pos_k<<<32, 256, 0, stream>>>(eidx, gatesA, cb, posa, wslotA);
  scatter_k<<<NSLOT, 64, 0, stream>>>(x, eidx, posa, buf);

  // expert GEMM 1: (E,CAP,D) x (E,D,H) -> GELU -> (E,CAP,H)
  // 1-D grid: wg = e + 8*(nt + 32*mt); e fastest (XCD-affine), mt slowest (work-first)
  gemm128<DDIM, DDIM, HDIM, 1, 32, 1><<<4096, 256, 0, stream>>>(
      buf, w1t, b1, hbuf, 0, rowsN);

  // expert GEMM 2, split-K=2 in ONE dispatch: wg = e + 8*(nt + 8*(ks + 2*mt))
  gemm128<HDIM / 2, HDIM, DDIM, 0, 8, 2><<<2048, 256, 0, stream>>>(
      hbuf, w2t, b2, outeA, PSTRIDE, rowsN);

  // combine
  combine_k<<<TDIM, 256, 0, stream>>>(outeA, outeA + PSTRIDE, eidx, posa, wslotA, out);
}

// Round 13
// 300.765 us; speedup vs baseline: 2.1240x; 1.0589x over previous
//
#include <hip/hip_runtime.h>
#include <cstdint>
#include <cstddef>

#define TDIM 4096       // B*S tokens
#define DDIM 1024
#define HDIM 4096
#define EDIM 8
#define CAPD 2048
#define NSLOT 8192      // T*K
#define NROUTERBLK 1024

typedef _Float16 f16;
typedef _Float16 f16x2 __attribute__((ext_vector_type(2)));
typedef _Float16 f16x4 __attribute__((ext_vector_type(4)));
typedef _Float16 f16x8 __attribute__((ext_vector_type(8)));
typedef float f32x4 __attribute__((ext_vector_type(4)));

__device__ __forceinline__ void gload16(const void* g, void* l) {
  __builtin_amdgcn_global_load_lds(
      (const __attribute__((address_space(1))) unsigned int*)g,
      (__attribute__((address_space(3))) unsigned int*)l, 16, 0, 0);
}

__device__ __forceinline__ float gelu_fast(float x) {
  float y = 1.5957691216057308f * (x + 0.044715f * x * x * x);
  y = fminf(y, 60.f);
  float e = __expf(y);
  return x * e * __builtin_amdgcn_rcpf(e + 1.f);
}

// ---------------- transpose + f32->f16 convert: src (E,R,C) -> dst (E,C,R) ----------------
__global__ __launch_bounds__(256)
void transpose_cvt(const float* __restrict__ src, f16* __restrict__ dst, int R, int C) {
  __shared__ float tile[64][65];
  const int e = blockIdx.z;
  const int c0 = blockIdx.x * 64, r0 = blockIdx.y * 64;
  const int tid = threadIdx.x;
  const float* s = src + (size_t)e * R * C;
  f16* d = dst + (size_t)e * R * C;
  #pragma unroll
  for (int p = 0; p < 4; ++p) {
    const int row = p * 16 + (tid >> 4);
    const int col = (tid & 15) * 4;
    float4 v = *(const float4*)(s + (size_t)(r0 + row) * C + c0 + col);
    tile[row][col] = v.x; tile[row][col + 1] = v.y;
    tile[row][col + 2] = v.z; tile[row][col + 3] = v.w;
  }
  __syncthreads();
  #pragma unroll
  for (int p = 0; p < 4; ++p) {
    const int crow = p * 16 + (tid >> 4);
    const int q = (tid & 15) * 4;
    f16x4 o;
    #pragma unroll
    for (int j = 0; j < 4; ++j) o[j] = (f16)tile[q + j][crow];
    *(f16x4*)(d + (size_t)(c0 + crow) * R + r0 + q) = o;
  }
}

// ---------------- router ----------------
__global__ void router_k(const float* __restrict__ x, const float* __restrict__ rw,
                         int* __restrict__ eidx, float* __restrict__ gates,
                         float* __restrict__ bps) {
  __shared__ float lrw[EDIM * DDIM];
  __shared__ float wps[4][EDIM];
  const int tid = threadIdx.x, lane = tid & 63, wv = tid >> 6;
  for (int i = tid; i < EDIM * DDIM; i += 256) lrw[i] = rw[i];
  __syncthreads();
  const int t = blockIdx.x * 4 + wv;
  float acc[EDIM];
  #pragma unroll
  for (int e = 0; e < EDIM; ++e) acc[e] = 0.f;
  const float* xr = x + (size_t)t * DDIM;
  #pragma unroll
  for (int j = 0; j < DDIM / 64; ++j) {
    float xv = xr[j * 64 + lane];
    #pragma unroll
    for (int e = 0; e < EDIM; ++e) acc[e] += xv * lrw[e * DDIM + j * 64 + lane];
  }
  #pragma unroll
  for (int off = 32; off >= 1; off >>= 1) {
    #pragma unroll
    for (int e = 0; e < EDIM; ++e) acc[e] += __shfl_xor(acc[e], off);
  }
  float mx = acc[0];
  #pragma unroll
  for (int e = 1; e < EDIM; ++e) mx = fmaxf(mx, acc[e]);
  float p[EDIM], s = 0.f;
  #pragma unroll
  for (int e = 0; e < EDIM; ++e) { p[e] = expf(acc[e] - mx); s += p[e]; }
  float inv = 1.f / s;
  #pragma unroll
  for (int e = 0; e < EDIM; ++e) p[e] *= inv;
  int i1 = 0; float p1 = p[0];
  #pragma unroll
  for (int e = 1; e < EDIM; ++e) if (p[e] > p1) { p1 = p[e]; i1 = e; }
  int i2 = (i1 == 0) ? 1 : 0; float p2 = p[i2];
  #pragma unroll
  for (int e = 0; e < EDIM; ++e) if (e != i1 && p[e] > p2) { p2 = p[e]; i2 = e; }
  float gs = 1.f / (p1 + p2);
  if (lane == 0) {
    eidx[2 * t] = i1; eidx[2 * t + 1] = i2;
    gates[2 * t] = p1 * gs; gates[2 * t + 1] = p2 * gs;
    #pragma unroll
    for (int e = 0; e < EDIM; ++e) wps[wv][e] = p[e];
  }
  __syncthreads();
  if (tid < EDIM)
    bps[blockIdx.x * EDIM + tid] = wps[0][tid] + wps[1][tid] + wps[2][tid] + wps[3][tid];
}

// ---------------- per-chunk expert histogram ----------------
__global__ void count_k(const int* __restrict__ eidx, int* __restrict__ cc) {
  __shared__ int h[EDIM];
  const int tid = threadIdx.x;
  if (tid < EDIM) h[tid] = 0;
  __syncthreads();
  atomicAdd(&h[eidx[blockIdx.x * 256 + tid]], 1);
  __syncthreads();
  if (tid < EDIM) cc[blockIdx.x * EDIM + tid] = h[tid];
}

// ---------------- scan chunks, totals, lb_loss ----------------
__global__ void scan_k(const int* __restrict__ cc, const float* __restrict__ bps,
                       int* __restrict__ cb, int* __restrict__ counts,
                       int* __restrict__ rowsNeeded, float* __restrict__ lb_out) {
  __shared__ float red[32][EDIM];
  __shared__ int cnt_s[EDIM];
  const int tid = threadIdx.x;
  const int e = tid & 7, g = tid >> 3;
  float s = 0.f;
  for (int j = 0; j < 32; ++j) s += bps[(g + 32 * j) * EDIM + e];
  red[g][e] = s;
  __syncthreads();
  for (int st = 16; st >= 1; st >>= 1) {
    if (g < st) red[g][e] += red[g + st][e];
    __syncthreads();
  }
  if (tid < EDIM) {
    int base = 0;
    for (int c = 0; c < 32; ++c) { cb[c * EDIM + tid] = base; base += cc[c * EDIM + tid]; }
    counts[tid] = base;
    rowsNeeded[tid] = base < CAPD ? base : CAPD;
    cnt_s[tid] = base;
  }
  __syncthreads();
  if (tid == 0) {
    float lb = 0.f;
    for (int ee = 0; ee < EDIM; ++ee)
      lb += (red[0][ee] / (float)TDIM) * ((float)cnt_s[ee] / (float)NSLOT);
    lb_out[0] = lb * (float)EDIM;
  }
}

// ---------------- per-slot position via wave ballots (deterministic) ----------------
__global__ void pos_k(const int* __restrict__ eidx, const float* __restrict__ gates,
                      const int* __restrict__ cb, int* __restrict__ posa,
                      float* __restrict__ wslot) {
  __shared__ int wcnt[4][EDIM];
  const int tid = threadIdx.x, lane = tid & 63, wv = tid >> 6;
  const int slot = blockIdx.x * 256 + tid;
  const int e = eidx[slot];
  const unsigned long long below = (1ull << lane) - 1ull;
  int wavepos = 0;
  #pragma unroll
  for (int ee = 0; ee < EDIM; ++ee) {
    unsigned long long m = __ballot(e == ee);
    if (lane == 0) wcnt[wv][ee] = __popcll(m);
    if (e == ee) wavepos = __popcll(m & below);
  }
  __syncthreads();
  int off = 0;
  for (int w = 0; w < wv; ++w) off += wcnt[w][e];
  const int pos = cb[blockIdx.x * EDIM + e] + off + wavepos;
  posa[slot] = pos;
  wslot[slot] = (pos < CAPD) ? gates[slot] : 0.f;
}

// ---------------- scatter token rows -> f16 expert buffers ----------------
__global__ void scatter_k(const float* __restrict__ x, const int* __restrict__ eidx,
                          const int* __restrict__ posa, f16* __restrict__ buf) {
  const int s = blockIdx.x, lane = threadIdx.x;
  const int p = posa[s];
  if (p >= CAPD) return;
  const int e = eidx[s], tok = s >> 1;
  const float4* src = (const float4*)(x + (size_t)tok * DDIM);
  f16x4* dst = (f16x4*)(buf + ((size_t)e * CAPD + p) * DDIM);
  #pragma unroll
  for (int j = 0; j < DDIM / 4 / 64; ++j) {
    float4 v = src[j * 64 + lane];
    f16x4 o; o.x = (f16)v.x; o.y = (f16)v.y; o.z = (f16)v.z; o.w = (f16)v.w;
    dst[j * 64 + lane] = o;
  }
}

// ============ 128x128 f16 MFMA GEMM — m97-exact single-buffer + swizzle (r13) ============
// r12 showed 2 blocks/CU -> 613 TF; m97 reaches 874 with single 32KB buffer and 4-5
// resident blocks (cross-block overlap hides the drain barrier, m114). r13 drops the
// dbuf: per K-tile {STAGE x4; __syncthreads(); ds_read+MFMA; __syncthreads()}.
// __syncthreads() = full vmcnt/lgkmcnt drain + barrier -> race-free by construction.
// LDS 32KB: A[128][64] (16KB) | B[128][64] (16KB); T2 swizzle via pre-swizzled global
// source + XOR'd read offsets (rule #21). hh: 0=A rows0-63, 1=A rows64-127, 2=B r0-63,
// 3=B r64-127 (8KB quarters).
#define STAGE(hh, g) do { \
    const f16* s_ = sP[hh] + (g) * 64; \
    char* d_ = smem + (hh) * 8192 + wv * 1024; \
    gload16(s_, d_); \
    gload16(s_ + (size_t)32 * LD, d_ + 4096); \
  } while (0)

template<int KLEN, int LD, int N, int GELU, int NT, int NKS>
__global__ __launch_bounds__(256, 4)
void gemm128s(const f16* __restrict__ A, const f16* __restrict__ Bt,
              const float* __restrict__ bias, f16* __restrict__ C, size_t pstride,
              const int* __restrict__ rowsNeeded) {
  constexpr int NTT = KLEN / 64;           // K-tiles
  __shared__ __align__(128) char smem[32768];
  const int wg = blockIdx.x;
  const int e = wg & 7;
  const int r = wg >> 3;
  const int nt = r % NT;
  const int ks = (r / NT) % NKS;
  const int mt = r / (NT * NKS);
  if (mt * 128 >= rowsNeeded[e]) return;
  const int tid = threadIdx.x, lane = tid & 63, wv = tid >> 6;   // wv 0..3
  const int wr = wv >> 1, wc = wv & 1;     // 2 x 2 wave grid, per-wave 64x64 out
  const int ro = lane & 15, q4 = (lane >> 4) * 4;
  const int ko0b = (lane >> 4) * 16;       // k-offset bytes within 128B row
  const f16* aBase = A + ((size_t)e * CAPD + (size_t)mt * 128) * LD + (size_t)ks * KLEN;
  const f16* bBase = Bt + ((size_t)e * N + (size_t)nt * 128) * LD + (size_t)ks * KLEN;
  const int row0 = tid >> 3;               // 0..31 (second gload does row0+32)
  const int sw0 = ((tid & 7) ^ (row0 & 7)) * 8;   // pre-swizzled source col (elements)

  const f16* sP[4];
  sP[0] = aBase + (size_t)row0 * LD + sw0;
  sP[1] = sP[0] + (size_t)64 * LD;
  sP[2] = bBase + (size_t)row0 * LD + sw0;
  sP[3] = sP[2] + (size_t)64 * LD;

  // hoisted LDS read byte-offsets
  int aoffs[4][2], boffs[4][2];
  #pragma unroll
  for (int m = 0; m < 4; ++m)
    #pragma unroll
    for (int k = 0; k < 2; ++k) {
      const int rh = wr * 64 + m * 16 + ro;
      aoffs[m][k] = rh * 128 + ((k * 64 + ko0b) ^ ((rh & 7) << 4));
      const int rb = wc * 64 + m * 16 + ro;
      boffs[m][k] = 16384 + rb * 128 + ((k * 64 + ko0b) ^ ((rb & 7) << 4));
    }

  f32x4 acc[4][4];
  #pragma unroll
  for (int m = 0; m < 4; ++m)
    #pragma unroll
    for (int n = 0; n < 4; ++n) acc[m][n] = (f32x4){0.f, 0.f, 0.f, 0.f};

  #pragma unroll 1
  for (int t = 0; t < NTT; ++t) {
    STAGE(0, t); STAGE(1, t); STAGE(2, t); STAGE(3, t);
    __syncthreads();                        // drains vmcnt(0): tile staged, all waves
    f16x8 af[4][2], bf[4][2];
    #pragma unroll
    for (int m = 0; m < 4; ++m)
      #pragma unroll
      for (int k = 0; k < 2; ++k) {
        af[m][k] = *(const f16x8*)(smem + aoffs[m][k]);
        bf[m][k] = *(const f16x8*)(smem + boffs[m][k]);
      }
    #pragma unroll
    for (int k = 0; k < 2; ++k)
      #pragma unroll
      for (int m = 0; m < 4; ++m)
        #pragma unroll
        for (int n = 0; n < 4; ++n)
          acc[m][n] = __builtin_amdgcn_mfma_f32_16x16x32_f16(af[m][k], bf[n][k], acc[m][n], 0, 0, 0);
    __syncthreads();                        // drains lgkmcnt: safe to overwrite LDS
  }

  // ---- epilogue: per-wave 8KB LDS region, swizzled conflict-free, coalesced stores
  float bv[4];
  #pragma unroll
  for (int n = 0; n < 4; ++n)
    bv[n] = (ks == 0) ? bias[e * N + nt * 128 + wc * 64 + n * 16 + ro] : 0.f;
  f16* Ct = (f16*)(smem + wv * 8192);       // [64][64] f16, col-byte ^= ((row>>2)&3)<<5
  #pragma unroll
  for (int m = 0; m < 4; ++m)
    #pragma unroll
    for (int n = 0; n < 4; ++n)
      #pragma unroll
      for (int i = 0; i < 4; ++i) {
        const int row = m * 16 + q4 + i;
        float v = acc[m][n][i] + bv[n];
        if (GELU) v = gelu_fast(v);
        *(f16*)((char*)Ct + row * 128 + (((n * 16 + ro) * 2) ^ (((row >> 2) & 3) << 5))) = (f16)v;
      }
  asm volatile("s_waitcnt lgkmcnt(0)" ::: "memory");
  __builtin_amdgcn_sched_barrier(0);
  f16* Cp = C + (size_t)ks * pstride;
  const size_t crow0 = (size_t)e * CAPD + mt * 128 + wr * 64;
  const int ccol0 = nt * 128 + wc * 64;
  #pragma unroll
  for (int j = 0; j < 8; ++j) {
    const int idx = j * 64 + lane;
    const int rr = idx >> 3, c2 = (idx & 7) * 16;
    f16x8 v = *(const f16x8*)((const char*)Ct + rr * 128 + (c2 ^ (((rr >> 2) & 3) << 5)));
    *(f16x8*)(Cp + (crow0 + rr) * N + ccol0 + (idx & 7) * 8) = v;
  }
}

// ---------------- combine: out[t] = sum_k wslot * (partA[row] + partB[row]) ----------------
__global__ void combine_k(const f16* __restrict__ pA, const f16* __restrict__ pB,
                          const int* __restrict__ eidx, const int* __restrict__ posa,
                          const float* __restrict__ wslot, float* __restrict__ out) {
  const int t = blockIdx.x, tid = threadIdx.x;
  const int s0 = 2 * t, s1 = 2 * t + 1;
  const int e0 = eidx[s0], e1 = eidx[s1];
  int p0 = posa[s0]; p0 = p0 < CAPD - 1 ? p0 : CAPD - 1;
  int p1 = posa[s1]; p1 = p1 < CAPD - 1 ? p1 : CAPD - 1;
  const float g0 = wslot[s0], g1 = wslot[s1];
  const size_t o0 = ((size_t)e0 * CAPD + p0) * DDIM;
  const size_t o1 = ((size_t)e1 * CAPD + p1) * DDIM;
  const f16x2* r0a = (const f16x2*)(pA + o0);
  const f16x2* r0b = (const f16x2*)(pB + o0);
  const f16x2* r1a = (const f16x2*)(pA + o1);
  const f16x2* r1b = (const f16x2*)(pB + o1);
  float2* o = (float2*)(out + (size_t)t * DDIM);
  #pragma unroll
  for (int j = tid; j < DDIM / 2; j += 256) {
    f16x2 a0 = r0a[j], a1 = r0b[j], b0 = r1a[j], b1 = r1b[j];
    o[j] = make_float2(
        g0 * ((float)a0.x + (float)a1.x) + g1 * ((float)b0.x + (float)b1.x),
        g0 * ((float)a0.y + (float)a1.y) + g1 * ((float)b0.y + (float)b1.y));
  }
}

extern "C" void kernel_launch(void* const* d_in, const int* in_sizes, int n_in,
                              void* d_out, int out_size, void* d_ws, size_t ws_size,
                              hipStream_t stream) {
  (void)in_sizes; (void)n_in; (void)out_size; (void)ws_size;
  const float* x  = (const float*)d_in[0];
  const float* rw = (const float*)d_in[1];
  const float* w1 = (const float*)d_in[2];
  const float* b1 = (const float*)d_in[3];
  const float* w2 = (const float*)d_in[4];
  const float* b2 = (const float*)d_in[5];
  float* out = (float*)d_out;

  char* ws = (char*)d_ws;
  size_t off = 0;
  auto alloc = [&](size_t b) { void* p = ws + off; off += (b + 255) & ~(size_t)255; return p; };
  f16* w1t   = (f16*)alloc((size_t)EDIM * DDIM * HDIM * 2);   // (E,H,D)
  f16* w2t   = (f16*)alloc((size_t)EDIM * DDIM * HDIM * 2);   // (E,D,H)
  f16* buf   = (f16*)alloc((size_t)EDIM * CAPD * DDIM * 2);   // (E,CAP,D)
  f16* hbuf  = (f16*)alloc((size_t)EDIM * CAPD * HDIM * 2);   // (E,CAP,H)
  const size_t PSTRIDE = (size_t)EDIM * CAPD * DDIM;
  f16* outeA = (f16*)alloc(PSTRIDE * 2);                       // split-K partial 0
  f16* outeB = (f16*)alloc(PSTRIDE * 2);                       // split-K partial 1 (contiguous)
  int*   eidx   = (int*)alloc(NSLOT * 4);
  int*   posa   = (int*)alloc(NSLOT * 4);
  float* gatesA = (float*)alloc(NSLOT * 4);
  float* wslotA = (float*)alloc(NSLOT * 4);
  int*   cc     = (int*)alloc(32 * EDIM * 4);
  int*   cb     = (int*)alloc(32 * EDIM * 4);
  int*   counts = (int*)alloc(EDIM * 4);
  int*   rowsN  = (int*)alloc(EDIM * 4);
  float* bps    = (float*)alloc(NROUTERBLK * EDIM * 4);
  (void)outeB;

  // weight conversion (independent of routing chain)
  transpose_cvt<<<dim3(HDIM / 64, DDIM / 64, EDIM), 256, 0, stream>>>(w1, w1t, DDIM, HDIM);
  transpose_cvt<<<dim3(DDIM / 64, HDIM / 64, EDIM), 256, 0, stream>>>(w2, w2t, HDIM, DDIM);

  // routing chain
  router_k<<<NROUTERBLK, 256, 0, stream>>>(x, rw, eidx, gatesA, bps);
  count_k<<<32, 256, 0, stream>>>(eidx, cc);
  scan_k<<<1, 256, 0, stream>>>(cc, bps, cb, counts, rowsN, out + (size_t)TDIM * DDIM);
  pos_k<<<32, 256, 0, stream>>>(eidx, gatesA, cb, posa, wslotA);
  scatter_k<<<NSLOT, 64, 0, stream>>>(x, eidx, posa, buf);

  // expert GEMM 1: (E,CAP,D) x (E,D,H) -> GELU -> (E,CAP,H)
  // 1-D grid: wg = e + 8*(nt + 32*mt); e fastest (XCD-affine), mt slowest (work-first)
  gemm128s<DDIM, DDIM, HDIM, 1, 32, 1><<<4096, 256, 0, stream>>>(
      buf, w1t, b1, hbuf, 0, rowsN);

  // expert GEMM 2, split-K=2 in ONE dispatch: wg = e + 8*(nt + 8*(ks + 2*mt))
  gemm128s<HDIM / 2, HDIM, DDIM, 0, 8, 2><<<2048, 256, 0, stream>>>(
      hbuf, w2t, b2, outeA, PSTRIDE, rowsN);

  // combine
  combine_k<<<TDIM, 256, 0, stream>>>(outeA, outeA + PSTRIDE, eidx, posa, wslotA, out);
}

// Round 14
// 294.981 us; speedup vs baseline: 2.1657x; 1.0196x over previous
//
#include <hip/hip_runtime.h>
#include <cstdint>
#include <cstddef>

#define TDIM 4096       // B*S tokens
#define DDIM 1024
#define HDIM 4096
#define EDIM 8
#define CAPD 2048
#define NSLOT 8192      // T*K
#define NROUTERBLK 1024

typedef _Float16 f16;
typedef _Float16 f16x2 __attribute__((ext_vector_type(2)));
typedef _Float16 f16x4 __attribute__((ext_vector_type(4)));
typedef _Float16 f16x8 __attribute__((ext_vector_type(8)));
typedef float f32x4 __attribute__((ext_vector_type(4)));

__device__ __forceinline__ void gload16(const void* g, void* l) {
  __builtin_amdgcn_global_load_lds(
      (const __attribute__((address_space(1))) unsigned int*)g,
      (__attribute__((address_space(3))) unsigned int*)l, 16, 0, 0);
}

__device__ __forceinline__ float gelu_fast(float x) {
  float y = 1.5957691216057308f * (x + 0.044715f * x * x * x);
  y = fminf(y, 60.f);
  float e = __expf(y);
  return x * e * __builtin_amdgcn_rcpf(e + 1.f);
}

// ---------------- transpose + f32->f16 convert: src (E,R,C) -> dst (E,C,R) ----------------
__global__ __launch_bounds__(256)
void transpose_cvt(const float* __restrict__ src, f16* __restrict__ dst, int R, int C) {
  __shared__ float tile[64][65];
  const int e = blockIdx.z;
  const int c0 = blockIdx.x * 64, r0 = blockIdx.y * 64;
  const int tid = threadIdx.x;
  const float* s = src + (size_t)e * R * C;
  f16* d = dst + (size_t)e * R * C;
  #pragma unroll
  for (int p = 0; p < 4; ++p) {
    const int row = p * 16 + (tid >> 4);
    const int col = (tid & 15) * 4;
    float4 v = *(const float4*)(s + (size_t)(r0 + row) * C + c0 + col);
    tile[row][col] = v.x; tile[row][col + 1] = v.y;
    tile[row][col + 2] = v.z; tile[row][col + 3] = v.w;
  }
  __syncthreads();
  #pragma unroll
  for (int p = 0; p < 4; ++p) {
    const int crow = p * 16 + (tid >> 4);
    const int q = (tid & 15) * 4;
    f16x4 o;
    #pragma unroll
    for (int j = 0; j < 4; ++j) o[j] = (f16)tile[q + j][crow];
    *(f16x4*)(d + (size_t)(c0 + crow) * R + r0 + q) = o;
  }
}

// ---------------- router ----------------
__global__ void router_k(const float* __restrict__ x, const float* __restrict__ rw,
                         int* __restrict__ eidx, float* __restrict__ gates,
                         float* __restrict__ bps) {
  __shared__ float lrw[EDIM * DDIM];
  __shared__ float wps[4][EDIM];
  const int tid = threadIdx.x, lane = tid & 63, wv = tid >> 6;
  for (int i = tid; i < EDIM * DDIM; i += 256) lrw[i] = rw[i];
  __syncthreads();
  const int t = blockIdx.x * 4 + wv;
  float acc[EDIM];
  #pragma unroll
  for (int e = 0; e < EDIM; ++e) acc[e] = 0.f;
  const float* xr = x + (size_t)t * DDIM;
  #pragma unroll
  for (int j = 0; j < DDIM / 64; ++j) {
    float xv = xr[j * 64 + lane];
    #pragma unroll
    for (int e = 0; e < EDIM; ++e) acc[e] += xv * lrw[e * DDIM + j * 64 + lane];
  }
  #pragma unroll
  for (int off = 32; off >= 1; off >>= 1) {
    #pragma unroll
    for (int e = 0; e < EDIM; ++e) acc[e] += __shfl_xor(acc[e], off);
  }
  float mx = acc[0];
  #pragma unroll
  for (int e = 1; e < EDIM; ++e) mx = fmaxf(mx, acc[e]);
  float p[EDIM], s = 0.f;
  #pragma unroll
  for (int e = 0; e < EDIM; ++e) { p[e] = expf(acc[e] - mx); s += p[e]; }
  float inv = 1.f / s;
  #pragma unroll
  for (int e = 0; e < EDIM; ++e) p[e] *= inv;
  int i1 = 0; float p1 = p[0];
  #pragma unroll
  for (int e = 1; e < EDIM; ++e) if (p[e] > p1) { p1 = p[e]; i1 = e; }
  int i2 = (i1 == 0) ? 1 : 0; float p2 = p[i2];
  #pragma unroll
  for (int e = 0; e < EDIM; ++e) if (e != i1 && p[e] > p2) { p2 = p[e]; i2 = e; }
  float gs = 1.f / (p1 + p2);
  if (lane == 0) {
    eidx[2 * t] = i1; eidx[2 * t + 1] = i2;
    gates[2 * t] = p1 * gs; gates[2 * t + 1] = p2 * gs;
    #pragma unroll
    for (int e = 0; e < EDIM; ++e) wps[wv][e] = p[e];
  }
  __syncthreads();
  if (tid < EDIM)
    bps[blockIdx.x * EDIM + tid] = wps[0][tid] + wps[1][tid] + wps[2][tid] + wps[3][tid];
}

// ---------------- per-chunk expert histogram ----------------
__global__ void count_k(const int* __restrict__ eidx, int* __restrict__ cc) {
  __shared__ int h[EDIM];
  const int tid = threadIdx.x;
  if (tid < EDIM) h[tid] = 0;
  __syncthreads();
  atomicAdd(&h[eidx[blockIdx.x * 256 + tid]], 1);
  __syncthreads();
  if (tid < EDIM) cc[blockIdx.x * EDIM + tid] = h[tid];
}

// ---------------- scan chunks, totals, lb_loss ----------------
__global__ void scan_k(const int* __restrict__ cc, const float* __restrict__ bps,
                       int* __restrict__ cb, int* __restrict__ counts,
                       int* __restrict__ rowsNeeded, float* __restrict__ lb_out) {
  __shared__ float red[32][EDIM];
  __shared__ int cnt_s[EDIM];
  const int tid = threadIdx.x;
  const int e = tid & 7, g = tid >> 3;
  float s = 0.f;
  for (int j = 0; j < 32; ++j) s += bps[(g + 32 * j) * EDIM + e];
  red[g][e] = s;
  __syncthreads();
  for (int st = 16; st >= 1; st >>= 1) {
    if (g < st) red[g][e] += red[g + st][e];
    __syncthreads();
  }
  if (tid < EDIM) {
    int base = 0;
    for (int c = 0; c < 32; ++c) { cb[c * EDIM + tid] = base; base += cc[c * EDIM + tid]; }
    counts[tid] = base;
    rowsNeeded[tid] = base < CAPD ? base : CAPD;
    cnt_s[tid] = base;
  }
  __syncthreads();
  if (tid == 0) {
    float lb = 0.f;
    for (int ee = 0; ee < EDIM; ++ee)
      lb += (red[0][ee] / (float)TDIM) * ((float)cnt_s[ee] / (float)NSLOT);
    lb_out[0] = lb * (float)EDIM;
  }
}

// ---------------- per-slot position via wave ballots (deterministic) ----------------
__global__ void pos_k(const int* __restrict__ eidx, const float* __restrict__ gates,
                      const int* __restrict__ cb, int* __restrict__ posa,
                      float* __restrict__ wslot) {
  __shared__ int wcnt[4][EDIM];
  const int tid = threadIdx.x, lane = tid & 63, wv = tid >> 6;
  const int slot = blockIdx.x * 256 + tid;
  const int e = eidx[slot];
  const unsigned long long below = (1ull << lane) - 1ull;
  int wavepos = 0;
  #pragma unroll
  for (int ee = 0; ee < EDIM; ++ee) {
    unsigned long long m = __ballot(e == ee);
    if (lane == 0) wcnt[wv][ee] = __popcll(m);
    if (e == ee) wavepos = __popcll(m & below);
  }
  __syncthreads();
  int off = 0;
  for (int w = 0; w < wv; ++w) off += wcnt[w][e];
  const int pos = cb[blockIdx.x * EDIM + e] + off + wavepos;
  posa[slot] = pos;
  wslot[slot] = (pos < CAPD) ? gates[slot] : 0.f;
}

// ---------------- scatter: one block per TOKEN, x-row read once, both slots written ----------------
__global__ void scatter2_k(const float* __restrict__ x, const int* __restrict__ eidx,
                           const int* __restrict__ posa, f16* __restrict__ buf) {
  const int t = blockIdx.x, lane = threadIdx.x;   // 64 threads
  const int s0 = 2 * t, s1 = 2 * t + 1;
  const int p0 = posa[s0], p1 = posa[s1];
  const int e0 = eidx[s0], e1 = eidx[s1];
  const float4* src = (const float4*)(x + (size_t)t * DDIM);
  f16x4* d0 = (f16x4*)(buf + ((size_t)e0 * CAPD + p0) * DDIM);
  f16x4* d1 = (f16x4*)(buf + ((size_t)e1 * CAPD + p1) * DDIM);
  const bool w0 = p0 < CAPD, w1 = p1 < CAPD;
  #pragma unroll
  for (int j = 0; j < DDIM / 4 / 64; ++j) {
    float4 v = src[j * 64 + lane];
    f16x4 o; o.x = (f16)v.x; o.y = (f16)v.y; o.z = (f16)v.z; o.w = (f16)v.w;
    if (w0) d0[j * 64 + lane] = o;
    if (w1) d1[j * 64 + lane] = o;
  }
}

// ============ 128x128 f16 MFMA GEMM — r13 structure + L2-banded grid (r14) ============
// e = wg&7 == XCD (round-robin dispatch): one expert per XCD, 4MB private L2.
// GEMM1's per-expert B set = 32 panels x 256KB = 8MB > 4MB -> nt split into halves
// of NTH=16 (4MB, L2-fit); nth is the SLOWEST dim so a half completes before the
// next starts -> B fetched ~once per half instead of once per mt-round.
// Decode: r=wg>>3; ntl=r%NTH; ks=(r/NTH)%NKS; mt=(r/NTH/NKS)%NMT; nth=r/(NTH*NKS*NMT).
// K-loop unchanged from r13 (single 32KB buffer, full-drain __syncthreads, 4 blk/CU).
#define STAGE(hh, g) do { \
    const f16* s_ = sP[hh] + (g) * 64; \
    char* d_ = smem + (hh) * 8192 + wv * 1024; \
    gload16(s_, d_); \
    gload16(s_ + (size_t)32 * LD, d_ + 4096); \
  } while (0)

template<int KLEN, int LD, int N, int GELU, int NTH, int NKS, int NMT>
__global__ __launch_bounds__(256, 4)
void gemm128s(const f16* __restrict__ A, const f16* __restrict__ Bt,
              const float* __restrict__ bias, f16* __restrict__ C, size_t pstride,
              const int* __restrict__ rowsNeeded) {
  constexpr int NTT = KLEN / 64;           // K-tiles
  __shared__ __align__(128) char smem[32768];
  const int wg = blockIdx.x;
  const int e = wg & 7;
  const int r = wg >> 3;
  const int ntl = r % NTH;
  const int ks = (r / NTH) % NKS;
  const int mt = (r / (NTH * NKS)) % NMT;
  const int nth = r / (NTH * NKS * NMT);
  const int nt = nth * NTH + ntl;
  if (mt * 128 >= rowsNeeded[e]) return;
  const int tid = threadIdx.x, lane = tid & 63, wv = tid >> 6;   // wv 0..3
  const int wr = wv >> 1, wc = wv & 1;     // 2 x 2 wave grid, per-wave 64x64 out
  const int ro = lane & 15, q4 = (lane >> 4) * 4;
  const int ko0b = (lane >> 4) * 16;       // k-offset bytes within 128B row
  const f16* aBase = A + ((size_t)e * CAPD + (size_t)mt * 128) * LD + (size_t)ks * KLEN;
  const f16* bBase = Bt + ((size_t)e * N + (size_t)nt * 128) * LD + (size_t)ks * KLEN;
  const int row0 = tid >> 3;               // 0..31 (second gload does row0+32)
  const int sw0 = ((tid & 7) ^ (row0 & 7)) * 8;   // pre-swizzled source col (elements)

  const f16* sP[4];
  sP[0] = aBase + (size_t)row0 * LD + sw0;
  sP[1] = sP[0] + (size_t)64 * LD;
  sP[2] = bBase + (size_t)row0 * LD + sw0;
  sP[3] = sP[2] + (size_t)64 * LD;

  // hoisted LDS read byte-offsets
  int aoffs[4][2], boffs[4][2];
  #pragma unroll
  for (int m = 0; m < 4; ++m)
    #pragma unroll
    for (int k = 0; k < 2; ++k) {
      const int rh = wr * 64 + m * 16 + ro;
      aoffs[m][k] = rh * 128 + ((k * 64 + ko0b) ^ ((rh & 7) << 4));
      const int rb = wc * 64 + m * 16 + ro;
      boffs[m][k] = 16384 + rb * 128 + ((k * 64 + ko0b) ^ ((rb & 7) << 4));
    }

  f32x4 acc[4][4];
  #pragma unroll
  for (int m = 0; m < 4; ++m)
    #pragma unroll
    for (int n = 0; n < 4; ++n) acc[m][n] = (f32x4){0.f, 0.f, 0.f, 0.f};

  #pragma unroll 1
  for (int t = 0; t < NTT; ++t) {
    STAGE(0, t); STAGE(1, t); STAGE(2, t); STAGE(3, t);
    __syncthreads();                        // drains vmcnt(0): tile staged, all waves
    f16x8 af[4][2], bf[4][2];
    #pragma unroll
    for (int m = 0; m < 4; ++m)
      #pragma unroll
      for (int k = 0; k < 2; ++k) {
        af[m][k] = *(const f16x8*)(smem + aoffs[m][k]);
        bf[m][k] = *(const f16x8*)(smem + boffs[m][k]);
      }
    #pragma unroll
    for (int k = 0; k < 2; ++k)
      #pragma unroll
      for (int m = 0; m < 4; ++m)
        #pragma unroll
        for (int n = 0; n < 4; ++n)
          acc[m][n] = __builtin_amdgcn_mfma_f32_16x16x32_f16(af[m][k], bf[n][k], acc[m][n], 0, 0, 0);
    __syncthreads();                        // drains lgkmcnt: safe to overwrite LDS
  }

  // ---- epilogue: per-wave 8KB LDS region, swizzled conflict-free, coalesced stores
  float bv[4];
  #pragma unroll
  for (int n = 0; n < 4; ++n)
    bv[n] = (ks == 0) ? bias[e * N + nt * 128 + wc * 64 + n * 16 + ro] : 0.f;
  f16* Ct = (f16*)(smem + wv * 8192);       // [64][64] f16, col-byte ^= ((row>>2)&3)<<5
  #pragma unroll
  for (int m = 0; m < 4; ++m)
    #pragma unroll
    for (int n = 0; n < 4; ++n)
      #pragma unroll
      for (int i = 0; i < 4; ++i) {
        const int row = m * 16 + q4 + i;
        float v = acc[m][n][i] + bv[n];
        if (GELU) v = gelu_fast(v);
        *(f16*)((char*)Ct + row * 128 + (((n * 16 + ro) * 2) ^ (((row >> 2) & 3) << 5))) = (f16)v;
      }
  asm volatile("s_waitcnt lgkmcnt(0)" ::: "memory");
  __builtin_amdgcn_sched_barrier(0);
  f16* Cp = C + (size_t)ks * pstride;
  const size_t crow0 = (size_t)e * CAPD + mt * 128 + wr * 64;
  const int ccol0 = nt * 128 + wc * 64;
  #pragma unroll
  for (int j = 0; j < 8; ++j) {
    const int idx = j * 64 + lane;
    const int rr = idx >> 3, c2 = (idx & 7) * 16;
    f16x8 v = *(const f16x8*)((const char*)Ct + rr * 128 + (c2 ^ (((rr >> 2) & 3) << 5)));
    *(f16x8*)(Cp + (crow0 + rr) * N + ccol0 + (idx & 7) * 8) = v;
  }
}

// ---------------- combine: out[t] = sum_k wslot * (partA[row] + partB[row]) ----------------
__global__ void combine_k(const f16* __restrict__ pA, const f16* __restrict__ pB,
                          const int* __restrict__ eidx, const int* __restrict__ posa,
                          const float* __restrict__ wslot, float* __restrict__ out) {
  const int t = blockIdx.x, tid = threadIdx.x;
  const int s0 = 2 * t, s1 = 2 * t + 1;
  const int e0 = eidx[s0], e1 = eidx[s1];
  int p0 = posa[s0]; p0 = p0 < CAPD - 1 ? p0 : CAPD - 1;
  int p1 = posa[s1]; p1 = p1 < CAPD - 1 ? p1 : CAPD - 1;
  const float g0 = wslot[s0], g1 = wslot[s1];
  const size_t o0 = ((size_t)e0 * CAPD + p0) * DDIM;
  const size_t o1 = ((size_t)e1 * CAPD + p1) * DDIM;
  const f16x2* r0a = (const f16x2*)(pA + o0);
  const f16x2* r0b = (const f16x2*)(pB + o0);
  const f16x2* r1a = (const f16x2*)(pA + o1);
  const f16x2* r1b = (const f16x2*)(pB + o1);
  float2* o = (float2*)(out + (size_t)t * DDIM);
  #pragma unroll
  for (int j = tid; j < DDIM / 2; j += 256) {
    f16x2 a0 = r0a[j], a1 = r0b[j], b0 = r1a[j], b1 = r1b[j];
    o[j] = make_float2(
        g0 * ((float)a0.x + (float)a1.x) + g1 * ((float)b0.x + (float)b1.x),
        g0 * ((float)a0.y + (float)a1.y) + g1 * ((float)b0.y + (float)b1.y));
  }
}

extern "C" void kernel_launch(void* const* d_in, const int* in_sizes, int n_in,
                              void* d_out, int out_size, void* d_ws, size_t ws_size,
                              hipStream_t stream) {
  (void)in_sizes; (void)n_in; (void)out_size; (void)ws_size;
  const float* x  = (const float*)d_in[0];
  const float* rw = (const float*)d_in[1];
  const float* w1 = (const float*)d_in[2];
  const float* b1 = (const float*)d_in[3];
  const float* w2 = (const float*)d_in[4];
  const float* b2 = (const float*)d_in[5];
  float* out = (float*)d_out;

  char* ws = (char*)d_ws;
  size_t off = 0;
  auto alloc = [&](size_t b) { void* p = ws + off; off += (b + 255) & ~(size_t)255; return p; };
  f16* w1t   = (f16*)alloc((size_t)EDIM * DDIM * HDIM * 2);   // (E,H,D)
  f16* w2t   = (f16*)alloc((size_t)EDIM * DDIM * HDIM * 2);   // (E,D,H)
  f16* buf   = (f16*)alloc((size_t)EDIM * CAPD * DDIM * 2);   // (E,CAP,D)
  f16* hbuf  = (f16*)alloc((size_t)EDIM * CAPD * HDIM * 2);   // (E,CAP,H)
  const size_t PSTRIDE = (size_t)EDIM * CAPD * DDIM;
  f16* outeA = (f16*)alloc(PSTRIDE * 2);                       // split-K partial 0
  f16* outeB = (f16*)alloc(PSTRIDE * 2);                       // split-K partial 1 (contiguous)
  int*   eidx   = (int*)alloc(NSLOT * 4);
  int*   posa   = (int*)alloc(NSLOT * 4);
  float* gatesA = (float*)alloc(NSLOT * 4);
  float* wslotA = (float*)alloc(NSLOT * 4);
  int*   cc     = (int*)alloc(32 * EDIM * 4);
  int*   cb     = (int*)alloc(32 * EDIM * 4);
  int*   counts = (int*)alloc(EDIM * 4);
  int*   rowsN  = (int*)alloc(EDIM * 4);
  float* bps    = (float*)alloc(NROUTERBLK * EDIM * 4);
  (void)outeB;

  // weight conversion (independent of routing chain)
  transpose_cvt<<<dim3(HDIM / 64, DDIM / 64, EDIM), 256, 0, stream>>>(w1, w1t, DDIM, HDIM);
  transpose_cvt<<<dim3(DDIM / 64, HDIM / 64, EDIM), 256, 0, stream>>>(w2, w2t, HDIM, DDIM);

  // routing chain
  router_k<<<NROUTERBLK, 256, 0, stream>>>(x, rw, eidx, gatesA, bps);
  count_k<<<32, 256, 0, stream>>>(eidx, cc);
  scan_k<<<1, 256, 0, stream>>>(cc, bps, cb, counts, rowsN, out + (size_t)TDIM * DDIM);
  pos_k<<<32, 256, 0, stream>>>(eidx, gatesA, cb, posa, wslotA);
  scatter2_k<<<TDIM, 64, 0, stream>>>(x, eidx, posa, buf);

  // expert GEMM 1: (E,CAP,D) x (E,D,H) -> GELU -> (E,CAP,H)
  // banded grid: wg = e + 8*(ntl + 16*(mt + 16*nth)); NTH=16 (B half-set = 4MB = XCD L2)
  gemm128s<DDIM, DDIM, HDIM, 1, 16, 1, 16><<<4096, 256, 0, stream>>>(
      buf, w1t, b1, hbuf, 0, rowsN);

  // expert GEMM 2, split-K=2 in ONE dispatch; B set already L2-fits (NTH=NT=8)
  gemm128s<HDIM / 2, HDIM, DDIM, 0, 8, 2, 16><<<2048, 256, 0, stream>>>(
      hbuf, w2t, b2, outeA, PSTRIDE, rowsN);

  // combine
  combine_k<<<TDIM, 256, 0, stream>>>(outeA, outeA + PSTRIDE, eidx, posa, wslotA, out);
}